// Round 2
// baseline (930.156 us; speedup 1.0000x reference)
//
#include <hip/hip_runtime.h>
#include <cstdint>
#include <cstddef>

#define B_  8
#define C_  256
#define L_  2048
#define H_  4
#define HD_ 64

// ---------------------------------------------------------------------------
// helpers
// ---------------------------------------------------------------------------
__device__ __forceinline__ float gelu_exact(float v) {
  return 0.5f * v * (1.0f + erff(v * 0.70710678118654752440f));
}

__device__ __forceinline__ void fma16(float (&acc)[4][4], const float4 a, const float4 b) {
  acc[0][0] += a.x * b.x; acc[0][1] += a.x * b.y; acc[0][2] += a.x * b.z; acc[0][3] += a.x * b.w;
  acc[1][0] += a.y * b.x; acc[1][1] += a.y * b.y; acc[1][2] += a.y * b.z; acc[1][3] += a.y * b.w;
  acc[2][0] += a.z * b.x; acc[2][1] += a.z * b.y; acc[2][2] += a.z * b.z; acc[2][3] += a.z * b.w;
  acc[3][0] += a.w * b.x; acc[3][1] += a.w * b.y; acc[3][2] += a.w * b.z; acc[3][3] += a.w * b.w;
}

// ---------------------------------------------------------------------------
// transpose: x[B][C][L] -> Xr[B][L][C]
// ---------------------------------------------------------------------------
__global__ __launch_bounds__(256) void k_transpose(const float* __restrict__ x,
                                                   float* __restrict__ Xr) {
  __shared__ float t[32][33];
  const int l0 = blockIdx.x * 32;
  const int c0 = blockIdx.y * 32;
  const int b  = blockIdx.z;
  const int tx = threadIdx.x;   // 0..31
  const int ty = threadIdx.y;   // 0..7
  const float* xp  = x  + (size_t)b * C_ * L_;
  float*       xrp = Xr + (size_t)b * L_ * C_;
#pragma unroll
  for (int i = 0; i < 32; i += 8)
    t[ty + i][tx] = xp[(size_t)(c0 + ty + i) * L_ + (l0 + tx)];
  __syncthreads();
#pragma unroll
  for (int i = 0; i < 32; i += 8)
    xrp[(size_t)(l0 + ty + i) * C_ + (c0 + tx)] = t[tx][ty + i];
}

// ---------------------------------------------------------------------------
// fp32 GEMM: Cout[M,256] = act(A[M,256] @ W[256,256] + bias)
// 128x128 tile, BK=16, 256 threads, 2x2 split of 4x4 micro-tiles (64 acc)
// ---------------------------------------------------------------------------
__global__ __launch_bounds__(256) void k_gemm(const float* __restrict__ A,
                                              const float* __restrict__ W,
                                              const float* __restrict__ bias,
                                              float* __restrict__ Cout,
                                              int actGelu) {
  __shared__ float AsT[16][132];  // [k][m]
  __shared__ float Bs[16][132];   // [k][n]
  const int tid = threadIdx.x;
  const int tm = tid >> 4;        // 0..15
  const int tn = tid & 15;        // 0..15
  const int m0 = blockIdx.x * 128;
  const int n0 = blockIdx.y * 128;
  const int arow = tid >> 2;      // 0..63 -> rows arow, arow+64
  const int acg  = tid & 3;       // A col f4 group
  const int brow = tid >> 5;      // 0..7  -> k-rows brow, brow+8
  const int bnc  = tid & 31;      // B col f4 group
  float a00[4][4] = {}, a01[4][4] = {}, a10[4][4] = {}, a11[4][4] = {};
  for (int k0 = 0; k0 < 256; k0 += 16) {
    float4 av0 = *reinterpret_cast<const float4*>(&A[(size_t)(m0 + arow) * 256 + k0 + acg * 4]);
    float4 av1 = *reinterpret_cast<const float4*>(&A[(size_t)(m0 + 64 + arow) * 256 + k0 + acg * 4]);
    float4 wv0 = *reinterpret_cast<const float4*>(&W[(size_t)(k0 + brow) * 256 + n0 + bnc * 4]);
    float4 wv1 = *reinterpret_cast<const float4*>(&W[(size_t)(k0 + 8 + brow) * 256 + n0 + bnc * 4]);
    AsT[acg * 4 + 0][arow] = av0.x;
    AsT[acg * 4 + 1][arow] = av0.y;
    AsT[acg * 4 + 2][arow] = av0.z;
    AsT[acg * 4 + 3][arow] = av0.w;
    AsT[acg * 4 + 0][64 + arow] = av1.x;
    AsT[acg * 4 + 1][64 + arow] = av1.y;
    AsT[acg * 4 + 2][64 + arow] = av1.z;
    AsT[acg * 4 + 3][64 + arow] = av1.w;
    *reinterpret_cast<float4*>(&Bs[brow][bnc * 4]) = wv0;
    *reinterpret_cast<float4*>(&Bs[8 + brow][bnc * 4]) = wv1;
    __syncthreads();
#pragma unroll
    for (int kk = 0; kk < 16; ++kk) {
      float4 a0 = *reinterpret_cast<const float4*>(&AsT[kk][tm << 2]);
      float4 a1 = *reinterpret_cast<const float4*>(&AsT[kk][64 + (tm << 2)]);
      float4 b0 = *reinterpret_cast<const float4*>(&Bs[kk][tn << 2]);
      float4 b1 = *reinterpret_cast<const float4*>(&Bs[kk][64 + (tn << 2)]);
      fma16(a00, a0, b0);
      fma16(a01, a0, b1);
      fma16(a10, a1, b0);
      fma16(a11, a1, b1);
    }
    __syncthreads();
  }
  float4 bv0 = *reinterpret_cast<const float4*>(&bias[n0 + (tn << 2)]);
  float4 bv1 = *reinterpret_cast<const float4*>(&bias[n0 + 64 + (tn << 2)]);
#pragma unroll
  for (int i = 0; i < 4; ++i) {
    float4 o00 = make_float4(a00[i][0] + bv0.x, a00[i][1] + bv0.y, a00[i][2] + bv0.z, a00[i][3] + bv0.w);
    float4 o01 = make_float4(a01[i][0] + bv1.x, a01[i][1] + bv1.y, a01[i][2] + bv1.z, a01[i][3] + bv1.w);
    float4 o10 = make_float4(a10[i][0] + bv0.x, a10[i][1] + bv0.y, a10[i][2] + bv0.z, a10[i][3] + bv0.w);
    float4 o11 = make_float4(a11[i][0] + bv1.x, a11[i][1] + bv1.y, a11[i][2] + bv1.z, a11[i][3] + bv1.w);
    if (actGelu) {
      o00.x = gelu_exact(o00.x); o00.y = gelu_exact(o00.y); o00.z = gelu_exact(o00.z); o00.w = gelu_exact(o00.w);
      o01.x = gelu_exact(o01.x); o01.y = gelu_exact(o01.y); o01.z = gelu_exact(o01.z); o01.w = gelu_exact(o01.w);
      o10.x = gelu_exact(o10.x); o10.y = gelu_exact(o10.y); o10.z = gelu_exact(o10.z); o10.w = gelu_exact(o10.w);
      o11.x = gelu_exact(o11.x); o11.y = gelu_exact(o11.y); o11.z = gelu_exact(o11.z); o11.w = gelu_exact(o11.w);
    }
    *reinterpret_cast<float4*>(&Cout[(size_t)(m0 + (tm << 2) + i) * 256 + n0 + (tn << 2)]) = o00;
    *reinterpret_cast<float4*>(&Cout[(size_t)(m0 + (tm << 2) + i) * 256 + n0 + 64 + (tn << 2)]) = o01;
    *reinterpret_cast<float4*>(&Cout[(size_t)(m0 + 64 + (tm << 2) + i) * 256 + n0 + (tn << 2)]) = o10;
    *reinterpret_cast<float4*>(&Cout[(size_t)(m0 + 64 + (tm << 2) + i) * 256 + n0 + 64 + (tn << 2)]) = o11;
  }
}

// ---------------------------------------------------------------------------
// Gram partials: Gp[bh][chunk] = K_chunk^T @ K_chunk  (64x64), chunk = 256 rows
// grid (8, H, B), 256 threads
// ---------------------------------------------------------------------------
__global__ __launch_bounds__(256) void k_gram(const float* __restrict__ Kg,
                                              float* __restrict__ Gp) {
  __shared__ float Ks[64][68];
  const int tid = threadIdx.x;
  const int tm = tid >> 4;
  const int tn = tid & 15;
  const int chunk = blockIdx.x;
  const int h = blockIdx.y;
  const int b = blockIdx.z;
  const size_t base = (size_t)b * L_ * C_ + (size_t)h * HD_ + (size_t)chunk * 256 * C_;
  const int lr = tid >> 2;
  const int lf = tid & 3;
  float acc[4][4] = {};
  for (int st = 0; st < 4; ++st) {
    __syncthreads();
#pragma unroll
    for (int i = 0; i < 4; ++i) {
      int fg = lf * 4 + i;
      float4 v = *reinterpret_cast<const float4*>(&Kg[base + (size_t)(st * 64 + lr) * C_ + fg * 4]);
      *reinterpret_cast<float4*>(&Ks[lr][fg * 4]) = v;
    }
    __syncthreads();
#pragma unroll 16
    for (int r = 0; r < 64; ++r) {
      float4 a  = *reinterpret_cast<const float4*>(&Ks[r][tm << 2]);
      float4 b2 = *reinterpret_cast<const float4*>(&Ks[r][tn << 2]);
      fma16(acc, a, b2);
    }
  }
  const int bh = b * H_ + h;
  float* gp = Gp + ((size_t)bh * 8 + chunk) * 4096;
#pragma unroll
  for (int i = 0; i < 4; ++i)
    *reinterpret_cast<float4*>(&gp[((tm << 2) + i) * 64 + (tn << 2)]) =
        make_float4(acc[i][0], acc[i][1], acc[i][2], acc[i][3]);
}

__global__ __launch_bounds__(256) void k_gram_reduce(const float* __restrict__ Gp,
                                                     float* __restrict__ G) {
  const int bh = blockIdx.x;
  const int tid = threadIdx.x;
  for (int t = tid; t < 4096; t += 256) {
    float s = 0.f;
#pragma unroll
    for (int c = 0; c < 8; ++c) s += Gp[((size_t)bh * 8 + c) * 4096 + t];
    G[(size_t)bh * 4096 + t] = s;
  }
}

// ---------------------------------------------------------------------------
// attention: block = (64 q-rows, h, b). Row norm via q^T G q (Gram trick),
// then single pass: QK^T -> exp -> PV. No max subtraction (|s_norm| <= 1).
// ---------------------------------------------------------------------------
__global__ __launch_bounds__(256) void k_attn(const float* __restrict__ Qg,
                                              const float* __restrict__ Kg,
                                              const float* __restrict__ Vg,
                                              const float* __restrict__ Gm,
                                              float* __restrict__ AO) {
  __shared__ float QsT[64][68];   // [d][q]
  __shared__ float KP[64][68];    // K^T [d][k]; reused as P[k][q]
  __shared__ float Vs[64][68];    // G [e][d] during prologue; V [k][d] in loop
  __shared__ float stat[64];      // per q-row: 0.125/(norm+eps)
  const int tid = threadIdx.x;
  const int tm = tid >> 4;        // 0..15
  const int tn = tid & 15;        // 0..15
  const int q0 = blockIdx.x * 64;
  const int h  = blockIdx.y;
  const int b  = blockIdx.z;
  const int bh = b * H_ + h;
  const size_t base = (size_t)b * L_ * C_ + (size_t)h * HD_;
  const int lr = tid >> 2;        // 0..63
  const int lf = tid & 3;

  // load Q tile transposed + G into Vs
#pragma unroll
  for (int i = 0; i < 4; ++i) {
    int fg = lf * 4 + i;          // 0..15
    float4 v = *reinterpret_cast<const float4*>(&Qg[base + (size_t)(q0 + lr) * C_ + fg * 4]);
    QsT[fg * 4 + 0][lr] = v.x;
    QsT[fg * 4 + 1][lr] = v.y;
    QsT[fg * 4 + 2][lr] = v.z;
    QsT[fg * 4 + 3][lr] = v.w;
    float4 g = *reinterpret_cast<const float4*>(&Gm[(size_t)bh * 4096 + lr * 64 + fg * 4]);
    *reinterpret_cast<float4*>(&Vs[lr][fg * 4]) = g;
  }
  __syncthreads();

  // T = Q @ G (per-thread 4x4), then r2[i] = sum_d T[q][d] * Q[q][d]
  float t4[4][4] = {};
#pragma unroll 16
  for (int e = 0; e < 64; ++e) {
    float4 a  = *reinterpret_cast<const float4*>(&QsT[e][tm << 2]);
    float4 b2 = *reinterpret_cast<const float4*>(&Vs[e][tn << 2]);
    fma16(t4, a, b2);
  }
  float r2[4];
#pragma unroll
  for (int i = 0; i < 4; ++i) {
    r2[i] = t4[i][0] * QsT[(tn << 2) + 0][(tm << 2) + i]
          + t4[i][1] * QsT[(tn << 2) + 1][(tm << 2) + i]
          + t4[i][2] * QsT[(tn << 2) + 2][(tm << 2) + i]
          + t4[i][3] * QsT[(tn << 2) + 3][(tm << 2) + i];
#pragma unroll
    for (int o = 8; o; o >>= 1) r2[i] += __shfl_xor(r2[i], o);
  }
  if (tn == 0) {
#pragma unroll
    for (int i = 0; i < 4; ++i) {
      float norm = sqrtf(r2[i] * (1.0f / 64.0f));      // = ||scores_row/8||
      stat[(tm << 2) + i] = 0.125f / (norm + 1e-12f);  // combined scale
    }
  }
  __syncthreads();
  float scl[4];
#pragma unroll
  for (int i = 0; i < 4; ++i) scl[i] = stat[(tm << 2) + i];

  float l_sum[4] = {0.f, 0.f, 0.f, 0.f};
  float o_acc[4][4] = {};
  for (int kt = 0; kt < 32; ++kt) {
#pragma unroll
    for (int i = 0; i < 4; ++i) {
      int fg = lf * 4 + i;
      float4 kv = *reinterpret_cast<const float4*>(&Kg[base + (size_t)(kt * 64 + lr) * C_ + fg * 4]);
      KP[fg * 4 + 0][lr] = kv.x;
      KP[fg * 4 + 1][lr] = kv.y;
      KP[fg * 4 + 2][lr] = kv.z;
      KP[fg * 4 + 3][lr] = kv.w;
      float4 vv = *reinterpret_cast<const float4*>(&Vg[base + (size_t)(kt * 64 + lr) * C_ + fg * 4]);
      *reinterpret_cast<float4*>(&Vs[lr][fg * 4]) = vv;
    }
    __syncthreads();
    float s[4][4] = {};
#pragma unroll 16
    for (int d = 0; d < 64; ++d) {
      float4 a  = *reinterpret_cast<const float4*>(&QsT[d][tm << 2]);
      float4 b2 = *reinterpret_cast<const float4*>(&KP[d][tn << 2]);
      fma16(s, a, b2);
    }
    __syncthreads();   // all QK^T reads of KP done before P overwrites it
    float p[4][4];
#pragma unroll
    for (int i = 0; i < 4; ++i)
#pragma unroll
      for (int j = 0; j < 4; ++j) {
        p[i][j] = __expf(s[i][j] * scl[i]);
        l_sum[i] += p[i][j];
      }
#pragma unroll
    for (int j = 0; j < 4; ++j)
      *reinterpret_cast<float4*>(&KP[(tn << 2) + j][tm << 2]) =
          make_float4(p[0][j], p[1][j], p[2][j], p[3][j]);   // P[k][q]
    __syncthreads();
#pragma unroll 16
    for (int k = 0; k < 64; ++k) {
      float4 a  = *reinterpret_cast<const float4*>(&KP[k][tm << 2]);   // P[k][4q]
      float4 b2 = *reinterpret_cast<const float4*>(&Vs[k][tn << 2]);   // V[k][4d]
      fma16(o_acc, a, b2);
    }
    __syncthreads();   // before next iteration's loads overwrite KP/Vs
  }
#pragma unroll
  for (int i = 0; i < 4; ++i)
#pragma unroll
    for (int o = 8; o; o >>= 1) l_sum[i] += __shfl_xor(l_sum[i], o);
#pragma unroll
  for (int i = 0; i < 4; ++i) {
    float inv = 1.0f / l_sum[i];
    float4 o;
    o.x = o_acc[i][0] * inv;
    o.y = o_acc[i][1] * inv;
    o.z = o_acc[i][2] * inv;
    o.w = o_acc[i][3] * inv;
    *reinterpret_cast<float4*>(&AO[base + (size_t)(q0 + (tm << 2) + i) * C_ + (tn << 2)]) = o;
  }
}

// ---------------------------------------------------------------------------
// LayerNorm(C) + ELU + residual + transpose back to [B][C][L]
// block: 256 threads, 32 l-rows; coalesced [B][C][L] writes
// ---------------------------------------------------------------------------
__global__ __launch_bounds__(256) void k_ln(const float* __restrict__ PO,
                                            const float* __restrict__ x,
                                            const float* __restrict__ g,
                                            const float* __restrict__ bta,
                                            float* __restrict__ out) {
  __shared__ float buf[32][257];
  __shared__ float mu_s[32], rs_s[32];
  __shared__ float gs[256], bs[256];
  const int b  = blockIdx.y;
  const int l0 = blockIdx.x * 32;
  const int tid = threadIdx.x;
  gs[tid] = g[tid];
  bs[tid] = bta[tid];
#pragma unroll 8
  for (int r = 0; r < 32; ++r)
    buf[r][tid] = PO[((size_t)b * L_ + l0 + r) * C_ + tid];
  __syncthreads();
  {
    const int r  = tid >> 3;   // 0..31
    const int c0 = tid & 7;    // 0..7
    float s1 = 0.f;
#pragma unroll
    for (int i = 0; i < 32; ++i) s1 += buf[r][c0 + (i << 3)];
#pragma unroll
    for (int o = 4; o; o >>= 1) s1 += __shfl_xor(s1, o);
    float mu = s1 * (1.0f / 256.0f);
    float s2 = 0.f;
#pragma unroll
    for (int i = 0; i < 32; ++i) {
      float dv = buf[r][c0 + (i << 3)] - mu;
      s2 += dv * dv;
    }
#pragma unroll
    for (int o = 4; o; o >>= 1) s2 += __shfl_xor(s2, o);
    if (c0 == 0) {
      mu_s[r] = mu;
      rs_s[r] = rsqrtf(s2 * (1.0f / 256.0f) + 1e-5f);
    }
  }
  __syncthreads();
  const int tl = tid & 31;   // l within tile
  const int tc = tid >> 5;   // 0..7
  const float mu = mu_s[tl];
  const float rs = rs_s[tl];
#pragma unroll 8
  for (int c = tc; c < 256; c += 8) {
    float y = (buf[tl][c] - mu) * rs * gs[c] + bs[c];
    float e = (y > 0.f) ? y : (__expf(y) - 1.0f);   // ELU alpha=1
    size_t idx = ((size_t)b * C_ + c) * L_ + l0 + tl;
    out[idx] = e + x[idx];
  }
}

// ---------------------------------------------------------------------------
extern "C" void kernel_launch(void* const* d_in, const int* in_sizes, int n_in,
                              void* d_out, int out_size, void* d_ws, size_t ws_size,
                              hipStream_t stream) {
  const float* x_in = (const float*)d_in[0];
  const float* q_w1 = (const float*)d_in[1];
  const float* q_b1 = (const float*)d_in[2];
  const float* q_w2 = (const float*)d_in[3];
  const float* q_b2 = (const float*)d_in[4];
  const float* k_w1 = (const float*)d_in[5];
  const float* k_b1 = (const float*)d_in[6];
  const float* k_w2 = (const float*)d_in[7];
  const float* k_b2 = (const float*)d_in[8];
  const float* v_w1 = (const float*)d_in[9];
  const float* v_b1 = (const float*)d_in[10];
  const float* v_b2_ = (const float*)d_in[12];
  const float* v_w2 = (const float*)d_in[11];
  const float* o_w  = (const float*)d_in[13];
  const float* o_b  = (const float*)d_in[14];
  const float* ln_g = (const float*)d_in[15];
  const float* ln_b = (const float*)d_in[16];
  float* out = (float*)d_out;
  float* ws  = (float*)d_ws;

  const size_t NB = (size_t)B_ * L_ * C_;   // 4,194,304 elements (16 MB)
  float* Xr = ws;              // [B*L][C]; later reused as Vb
  float* Hb = ws + NB;         // MLP hidden; later AO
  float* Qb = ws + 2 * NB;     // Q; later PO
  float* Kb = ws + 3 * NB;     // K
  float* Gp = ws + 4 * NB;     // gram partials: 32*8*4096 floats (4 MB)
  float* G  = Gp + (size_t)32 * 8 * 4096;  // 32*4096 floats
  float* Vb = Xr;
  float* AO = Hb;
  float* PO = Qb;

  dim3 ggrid(B_ * L_ / 128, C_ / 128);   // (128, 2)

  k_transpose<<<dim3(L_ / 32, C_ / 32, B_), dim3(32, 8), 0, stream>>>(x_in, Xr);

  k_gemm<<<ggrid, 256, 0, stream>>>(Xr, q_w1, q_b1, Hb, 1);
  k_gemm<<<ggrid, 256, 0, stream>>>(Hb, q_w2, q_b2, Qb, 0);
  k_gemm<<<ggrid, 256, 0, stream>>>(Xr, k_w1, k_b1, Hb, 1);
  k_gemm<<<ggrid, 256, 0, stream>>>(Hb, k_w2, k_b2, Kb, 0);
  k_gemm<<<ggrid, 256, 0, stream>>>(Xr, v_w1, v_b1, Hb, 1);   // last read of Xr

  k_gram<<<dim3(8, H_, B_), 256, 0, stream>>>(Kb, Gp);
  k_gram_reduce<<<dim3(32), 256, 0, stream>>>(Gp, G);

  k_gemm<<<ggrid, 256, 0, stream>>>(Hb, v_w2, v_b2_, Vb, 0);  // Vb aliases Xr

  k_attn<<<dim3(L_ / 64, H_, B_), 256, 0, stream>>>(Qb, Kb, Vb, G, AO);

  k_gemm<<<ggrid, 256, 0, stream>>>(AO, o_w, o_b, PO, 0);     // PO aliases Qb

  k_ln<<<dim3(L_ / 32, B_), 256, 0, stream>>>(PO, x_in, ln_g, ln_b, out);
}

// Round 3
// 483.876 us; speedup vs baseline: 1.9223x; 1.9223x over previous
//
#include <hip/hip_runtime.h>
#include <hip/hip_bf16.h>
#include <cstdint>
#include <cstddef>

#define B_  8
#define C_  256
#define L_  2048
#define H_  4
#define HD_ 64

using short8v = __attribute__((ext_vector_type(8))) short;
using f32x4   = __attribute__((ext_vector_type(4))) float;

// ---------------------------------------------------------------------------
// helpers
// ---------------------------------------------------------------------------
__device__ __forceinline__ float gelu_exact(float v) {
  return 0.5f * v * (1.0f + erff(v * 0.70710678118654752440f));
}

__device__ __forceinline__ short f2bf(float v) {
  __hip_bfloat16 h = __float2bfloat16(v);
  return *reinterpret_cast<short*>(&h);
}

__device__ __forceinline__ void fma16(float (&acc)[4][4], const float4 a, const float4 b) {
  acc[0][0] += a.x * b.x; acc[0][1] += a.x * b.y; acc[0][2] += a.x * b.z; acc[0][3] += a.x * b.w;
  acc[1][0] += a.y * b.x; acc[1][1] += a.y * b.y; acc[1][2] += a.y * b.z; acc[1][3] += a.y * b.w;
  acc[2][0] += a.z * b.x; acc[2][1] += a.z * b.y; acc[2][2] += a.z * b.z; acc[2][3] += a.z * b.w;
  acc[3][0] += a.w * b.x; acc[3][1] += a.w * b.y; acc[3][2] += a.w * b.z; acc[3][3] += a.w * b.w;
}

// ---------------------------------------------------------------------------
// transpose: x[B][C][L] -> Xr[B][L][C]
// ---------------------------------------------------------------------------
__global__ __launch_bounds__(256) void k_transpose(const float* __restrict__ x,
                                                   float* __restrict__ Xr) {
  __shared__ float t[32][33];
  const int l0 = blockIdx.x * 32;
  const int c0 = blockIdx.y * 32;
  const int b  = blockIdx.z;
  const int tx = threadIdx.x;   // 0..31
  const int ty = threadIdx.y;   // 0..7
  const float* xp  = x  + (size_t)b * C_ * L_;
  float*       xrp = Xr + (size_t)b * L_ * C_;
#pragma unroll
  for (int i = 0; i < 32; i += 8)
    t[ty + i][tx] = xp[(size_t)(c0 + ty + i) * L_ + (l0 + tx)];
  __syncthreads();
#pragma unroll
  for (int i = 0; i < 32; i += 8)
    xrp[(size_t)(l0 + ty + i) * C_ + (c0 + tx)] = t[tx][ty + i];
}

// ---------------------------------------------------------------------------
// fp32 GEMM: Cout[M,256] = act(A[M,256] @ W[256,256] + bias), 128x128 tile
// ---------------------------------------------------------------------------
__global__ __launch_bounds__(256) void k_gemm(const float* __restrict__ A,
                                              const float* __restrict__ W,
                                              const float* __restrict__ bias,
                                              float* __restrict__ Cout,
                                              int actGelu) {
  __shared__ float AsT[16][132];  // [k][m]
  __shared__ float Bs[16][132];   // [k][n]
  const int tid = threadIdx.x;
  const int tm = tid >> 4;
  const int tn = tid & 15;
  const int m0 = blockIdx.x * 128;
  const int n0 = blockIdx.y * 128;
  const int arow = tid >> 2;
  const int acg  = tid & 3;
  const int brow = tid >> 5;
  const int bnc  = tid & 31;
  float a00[4][4] = {}, a01[4][4] = {}, a10[4][4] = {}, a11[4][4] = {};
  for (int k0 = 0; k0 < 256; k0 += 16) {
    float4 av0 = *reinterpret_cast<const float4*>(&A[(size_t)(m0 + arow) * 256 + k0 + acg * 4]);
    float4 av1 = *reinterpret_cast<const float4*>(&A[(size_t)(m0 + 64 + arow) * 256 + k0 + acg * 4]);
    float4 wv0 = *reinterpret_cast<const float4*>(&W[(size_t)(k0 + brow) * 256 + n0 + bnc * 4]);
    float4 wv1 = *reinterpret_cast<const float4*>(&W[(size_t)(k0 + 8 + brow) * 256 + n0 + bnc * 4]);
    AsT[acg * 4 + 0][arow] = av0.x;
    AsT[acg * 4 + 1][arow] = av0.y;
    AsT[acg * 4 + 2][arow] = av0.z;
    AsT[acg * 4 + 3][arow] = av0.w;
    AsT[acg * 4 + 0][64 + arow] = av1.x;
    AsT[acg * 4 + 1][64 + arow] = av1.y;
    AsT[acg * 4 + 2][64 + arow] = av1.z;
    AsT[acg * 4 + 3][64 + arow] = av1.w;
    *reinterpret_cast<float4*>(&Bs[brow][bnc * 4]) = wv0;
    *reinterpret_cast<float4*>(&Bs[8 + brow][bnc * 4]) = wv1;
    __syncthreads();
#pragma unroll
    for (int kk = 0; kk < 16; ++kk) {
      float4 a0 = *reinterpret_cast<const float4*>(&AsT[kk][tm << 2]);
      float4 a1 = *reinterpret_cast<const float4*>(&AsT[kk][64 + (tm << 2)]);
      float4 b0 = *reinterpret_cast<const float4*>(&Bs[kk][tn << 2]);
      float4 b1 = *reinterpret_cast<const float4*>(&Bs[kk][64 + (tn << 2)]);
      fma16(a00, a0, b0);
      fma16(a01, a0, b1);
      fma16(a10, a1, b0);
      fma16(a11, a1, b1);
    }
    __syncthreads();
  }
  float4 bv0 = *reinterpret_cast<const float4*>(&bias[n0 + (tn << 2)]);
  float4 bv1 = *reinterpret_cast<const float4*>(&bias[n0 + 64 + (tn << 2)]);
#pragma unroll
  for (int i = 0; i < 4; ++i) {
    float4 o00 = make_float4(a00[i][0] + bv0.x, a00[i][1] + bv0.y, a00[i][2] + bv0.z, a00[i][3] + bv0.w);
    float4 o01 = make_float4(a01[i][0] + bv1.x, a01[i][1] + bv1.y, a01[i][2] + bv1.z, a01[i][3] + bv1.w);
    float4 o10 = make_float4(a10[i][0] + bv0.x, a10[i][1] + bv0.y, a10[i][2] + bv0.z, a10[i][3] + bv0.w);
    float4 o11 = make_float4(a11[i][0] + bv1.x, a11[i][1] + bv1.y, a11[i][2] + bv1.z, a11[i][3] + bv1.w);
    if (actGelu) {
      o00.x = gelu_exact(o00.x); o00.y = gelu_exact(o00.y); o00.z = gelu_exact(o00.z); o00.w = gelu_exact(o00.w);
      o01.x = gelu_exact(o01.x); o01.y = gelu_exact(o01.y); o01.z = gelu_exact(o01.z); o01.w = gelu_exact(o01.w);
      o10.x = gelu_exact(o10.x); o10.y = gelu_exact(o10.y); o10.z = gelu_exact(o10.z); o10.w = gelu_exact(o10.w);
      o11.x = gelu_exact(o11.x); o11.y = gelu_exact(o11.y); o11.z = gelu_exact(o11.z); o11.w = gelu_exact(o11.w);
    }
    *reinterpret_cast<float4*>(&Cout[(size_t)(m0 + (tm << 2) + i) * 256 + n0 + (tn << 2)]) = o00;
    *reinterpret_cast<float4*>(&Cout[(size_t)(m0 + (tm << 2) + i) * 256 + n0 + 64 + (tn << 2)]) = o01;
    *reinterpret_cast<float4*>(&Cout[(size_t)(m0 + 64 + (tm << 2) + i) * 256 + n0 + (tn << 2)]) = o10;
    *reinterpret_cast<float4*>(&Cout[(size_t)(m0 + 64 + (tm << 2) + i) * 256 + n0 + 64 + (tn << 2)]) = o11;
  }
}

// ---------------------------------------------------------------------------
// Gram partials: Gp[bh][chunk] = K_chunk^T @ K_chunk (64x64), fp32
// ---------------------------------------------------------------------------
__global__ __launch_bounds__(256) void k_gram(const float* __restrict__ Kg,
                                              float* __restrict__ Gp) {
  __shared__ float Ks[64][68];
  const int tid = threadIdx.x;
  const int tm = tid >> 4;
  const int tn = tid & 15;
  const int chunk = blockIdx.x;
  const int h = blockIdx.y;
  const int b = blockIdx.z;
  const size_t base = (size_t)b * L_ * C_ + (size_t)h * HD_ + (size_t)chunk * 256 * C_;
  const int lr = tid >> 2;
  const int lf = tid & 3;
  float acc[4][4] = {};
  for (int st = 0; st < 4; ++st) {
    __syncthreads();
#pragma unroll
    for (int i = 0; i < 4; ++i) {
      int fg = lf * 4 + i;
      float4 v = *reinterpret_cast<const float4*>(&Kg[base + (size_t)(st * 64 + lr) * C_ + fg * 4]);
      *reinterpret_cast<float4*>(&Ks[lr][fg * 4]) = v;
    }
    __syncthreads();
#pragma unroll 16
    for (int r = 0; r < 64; ++r) {
      float4 a  = *reinterpret_cast<const float4*>(&Ks[r][tm << 2]);
      float4 b2 = *reinterpret_cast<const float4*>(&Ks[r][tn << 2]);
      fma16(acc, a, b2);
    }
  }
  const int bh = b * H_ + h;
  float* gp = Gp + ((size_t)bh * 8 + chunk) * 4096;
#pragma unroll
  for (int i = 0; i < 4; ++i)
    *reinterpret_cast<float4*>(&gp[((tm << 2) + i) * 64 + (tn << 2)]) =
        make_float4(acc[i][0], acc[i][1], acc[i][2], acc[i][3]);
}

__global__ __launch_bounds__(256) void k_gram_reduce(const float* __restrict__ Gp,
                                                     float* __restrict__ G) {
  const int bh = blockIdx.x;
  const int tid = threadIdx.x;
  for (int t = tid; t < 4096; t += 256) {
    float s = 0.f;
#pragma unroll
    for (int c = 0; c < 8; ++c) s += Gp[((size_t)bh * 8 + c) * 4096 + t];
    G[(size_t)bh * 4096 + t] = s;
  }
}

// ---------------------------------------------------------------------------
// per-row Lipschitz scale: Scl[bh][l] = 1 / (sqrt(q^T G q) + 8e-12)
// (normalized score = raw_QK * Scl; |normalized| <= ~1)
// ---------------------------------------------------------------------------
__global__ __launch_bounds__(256) void k_scale(const float* __restrict__ Qg,
                                               const float* __restrict__ Gm,
                                               float* __restrict__ Scl) {
  __shared__ float QsT[64][68];   // [d][q]
  __shared__ float Gs[64][68];    // [e][d]
  const int tid = threadIdx.x;
  const int tm = tid >> 4;
  const int tn = tid & 15;
  const int q0 = blockIdx.x * 64;
  const int h  = blockIdx.y;
  const int b  = blockIdx.z;
  const int bh = b * H_ + h;
  const size_t base = (size_t)b * L_ * C_ + (size_t)h * HD_;
  const int lr = tid >> 2;
  const int lf = tid & 3;
#pragma unroll
  for (int i = 0; i < 4; ++i) {
    int fg = lf * 4 + i;
    float4 v = *reinterpret_cast<const float4*>(&Qg[base + (size_t)(q0 + lr) * C_ + fg * 4]);
    QsT[fg * 4 + 0][lr] = v.x;
    QsT[fg * 4 + 1][lr] = v.y;
    QsT[fg * 4 + 2][lr] = v.z;
    QsT[fg * 4 + 3][lr] = v.w;
    float4 g = *reinterpret_cast<const float4*>(&Gm[(size_t)bh * 4096 + lr * 64 + fg * 4]);
    *reinterpret_cast<float4*>(&Gs[lr][fg * 4]) = g;
  }
  __syncthreads();
  float t4[4][4] = {};
#pragma unroll 16
  for (int e = 0; e < 64; ++e) {
    float4 a  = *reinterpret_cast<const float4*>(&QsT[e][tm << 2]);
    float4 b2 = *reinterpret_cast<const float4*>(&Gs[e][tn << 2]);
    fma16(t4, a, b2);
  }
  float r2[4];
#pragma unroll
  for (int i = 0; i < 4; ++i) {
    r2[i] = t4[i][0] * QsT[(tn << 2) + 0][(tm << 2) + i]
          + t4[i][1] * QsT[(tn << 2) + 1][(tm << 2) + i]
          + t4[i][2] * QsT[(tn << 2) + 2][(tm << 2) + i]
          + t4[i][3] * QsT[(tn << 2) + 3][(tm << 2) + i];
#pragma unroll
    for (int o = 8; o; o >>= 1) r2[i] += __shfl_xor(r2[i], o);
  }
  if (tn == 0) {
#pragma unroll
    for (int i = 0; i < 4; ++i) {
      float rr = fmaxf(r2[i], 0.f);
      Scl[(size_t)bh * L_ + q0 + (tm << 2) + i] = 1.0f / (sqrtf(rr) + 8e-12f);
    }
  }
}

// ---------------------------------------------------------------------------
// pack Q,K fp32 [B*L][C] -> bf16 [BH][L][64]
// ---------------------------------------------------------------------------
__global__ __launch_bounds__(256) void k_pack_qk(const float* __restrict__ Qf,
                                                 const float* __restrict__ Kf,
                                                 short* __restrict__ Qh,
                                                 short* __restrict__ Kh) {
  const int blk = blockIdx.x;    // 256 blocks x 64 rows
  const int tid = threadIdx.x;
#pragma unroll
  for (int i = 0; i < 16; ++i) {
    int idx = tid + 256 * i;     // 0..4095 = 64 rows x 64 float4
    int row = idx >> 6;
    int c4  = idx & 63;
    int R = blk * 64 + row;
    int b = R >> 11, l = R & 2047;
    int h = c4 >> 4, d4 = c4 & 15;
    size_t o = ((size_t)(b * H_ + h) * L_ + l) * HD_ + d4 * 4;
    float4 q = *reinterpret_cast<const float4*>(&Qf[(size_t)R * C_ + c4 * 4]);
    float4 k = *reinterpret_cast<const float4*>(&Kf[(size_t)R * C_ + c4 * 4]);
    short4 qs, ks;
    qs.x = f2bf(q.x); qs.y = f2bf(q.y); qs.z = f2bf(q.z); qs.w = f2bf(q.w);
    ks.x = f2bf(k.x); ks.y = f2bf(k.y); ks.z = f2bf(k.z); ks.w = f2bf(k.w);
    *reinterpret_cast<short4*>(&Qh[o]) = qs;
    *reinterpret_cast<short4*>(&Kh[o]) = ks;
  }
}

// ---------------------------------------------------------------------------
// pack+transpose V fp32 [B*L][C] -> bf16 Vt[BH][64 d][L]
// ---------------------------------------------------------------------------
__global__ __launch_bounds__(256) void k_packt_v(const float* __restrict__ Vf,
                                                 short* __restrict__ Vt) {
  __shared__ float T[64][65];
  const int lt = blockIdx.x;     // 0..31
  const int h = blockIdx.y, b = blockIdx.z;
  const int bh = b * H_ + h;
  const int tid = threadIdx.x;
#pragma unroll
  for (int i = 0; i < 4; ++i) {
    int idx = tid + 256 * i;     // 0..1023 = 64 l x 16 float4
    int l = idx >> 4;
    int c4 = idx & 15;
    float4 v = *reinterpret_cast<const float4*>(
        &Vf[(size_t)(b * L_ + lt * 64 + l) * C_ + h * HD_ + c4 * 4]);
    T[l][c4 * 4 + 0] = v.x;
    T[l][c4 * 4 + 1] = v.y;
    T[l][c4 * 4 + 2] = v.z;
    T[l][c4 * 4 + 3] = v.w;
  }
  __syncthreads();
  const int d  = tid >> 2;
  const int ls = (tid & 3) * 16;
#pragma unroll
  for (int i = 0; i < 4; ++i) {
    int l = ls + i * 4;
    short4 s;
    s.x = f2bf(T[l + 0][d]);
    s.y = f2bf(T[l + 1][d]);
    s.z = f2bf(T[l + 2][d]);
    s.w = f2bf(T[l + 3][d]);
    *reinterpret_cast<short4*>(&Vt[((size_t)bh * HD_ + d) * L_ + lt * 64 + l]) = s;
  }
}

// ---------------------------------------------------------------------------
// MFMA attention: block = 128 q rows, 4 waves (32 q each), 64-key tiles.
// Fragment maps (learn_hip-verified): A row=l&15,k=(l>>4)*8+j; B col=l&15;
// C row=(l>>4)*4+reg, col=l&15. LDS tiles XOR-swizzled: elem ^= (row&7)<<3.
// ---------------------------------------------------------------------------
__device__ __forceinline__ int swz(int r, int c) {
  return (r * 64 + c) ^ ((r & 7) << 3);
}

__global__ __launch_bounds__(256) void k_attn_mfma(
    const short* __restrict__ Qh, const short* __restrict__ Kh,
    const short* __restrict__ Vt, const float* __restrict__ Scl,
    float* __restrict__ AO) {
  __shared__ short Ks[2][64 * 64];   // [buf] K[key][d] swizzled
  __shared__ short Vs[2][64 * 64];   // [buf] V^T[d][key] swizzled
  __shared__ short Ps[4][32 * 64];   // per-wave P[q][key] swizzled
  const int tid  = threadIdx.x;
  const int lane = tid & 63;
  const int w    = tid >> 6;
  const int h = blockIdx.y, b = blockIdx.z;
  const int bh = b * H_ + h;
  const size_t hb = (size_t)bh * L_ * HD_;
  const int q0 = blockIdx.x * 128 + w * 32;
  const int l15 = lane & 15;
  const int lg  = lane >> 4;         // 0..3
  const int srow = tid >> 3;         // 0..31
  const int sseg = tid & 7;          // 0..7

  // Q A-frags in registers: aq[sub][chunk]
  bfragdecl:;
  short8v aq[2][2];
#pragma unroll
  for (int sub = 0; sub < 2; ++sub)
#pragma unroll
    for (int ch = 0; ch < 2; ++ch)
      aq[sub][ch] = *reinterpret_cast<const short8v*>(
          &Qh[hb + (size_t)(q0 + sub * 16 + l15) * HD_ + ch * 32 + lg * 8]);

  float sr[2][4];
#pragma unroll
  for (int sub = 0; sub < 2; ++sub)
#pragma unroll
    for (int r = 0; r < 4; ++r)
      sr[sub][r] = Scl[(size_t)bh * L_ + q0 + sub * 16 + lg * 4 + r];

  short8v stK0, stK1, stV0, stV1;
  auto stage_load = [&](int kt) {
    stK0 = *reinterpret_cast<const short8v*>(&Kh[hb + (size_t)(kt * 64 + srow) * HD_ + sseg * 8]);
    stK1 = *reinterpret_cast<const short8v*>(&Kh[hb + (size_t)(kt * 64 + 32 + srow) * HD_ + sseg * 8]);
    stV0 = *reinterpret_cast<const short8v*>(&Vt[hb + (size_t)srow * L_ + kt * 64 + sseg * 8]);
    stV1 = *reinterpret_cast<const short8v*>(&Vt[hb + (size_t)(32 + srow) * L_ + kt * 64 + sseg * 8]);
  };
  auto stage_write = [&](int buf) {
    *reinterpret_cast<short8v*>(&Ks[buf][swz(srow, sseg * 8)]) = stK0;
    *reinterpret_cast<short8v*>(&Ks[buf][swz(32 + srow, sseg * 8)]) = stK1;
    *reinterpret_cast<short8v*>(&Vs[buf][swz(srow, sseg * 8)]) = stV0;
    *reinterpret_cast<short8v*>(&Vs[buf][swz(32 + srow, sseg * 8)]) = stV1;
  };

  const f32x4 z4 = {0.f, 0.f, 0.f, 0.f};
  float lsum[2][4] = {};
  f32x4 oacc[2][4];
#pragma unroll
  for (int s = 0; s < 2; ++s)
#pragma unroll
    for (int d = 0; d < 4; ++d) oacc[s][d] = z4;

  stage_load(0);
  stage_write(0);
  __syncthreads();

  for (int kt = 0; kt < 32; ++kt) {
    const int cur = kt & 1;
    if (kt < 31) stage_load(kt + 1);

    // ---- QK^T ----
    f32x4 sacc[2][4];
#pragma unroll
    for (int s = 0; s < 2; ++s)
#pragma unroll
      for (int nt = 0; nt < 4; ++nt) sacc[s][nt] = z4;
#pragma unroll
    for (int nt = 0; nt < 4; ++nt) {
      short8v kb0 = *reinterpret_cast<const short8v*>(&Ks[cur][swz(nt * 16 + l15, lg * 8)]);
      short8v kb1 = *reinterpret_cast<const short8v*>(&Ks[cur][swz(nt * 16 + l15, 32 + lg * 8)]);
#pragma unroll
      for (int sub = 0; sub < 2; ++sub) {
        sacc[sub][nt] = __builtin_amdgcn_mfma_f32_16x16x32_bf16(aq[sub][0], kb0, sacc[sub][nt], 0, 0, 0);
        sacc[sub][nt] = __builtin_amdgcn_mfma_f32_16x16x32_bf16(aq[sub][1], kb1, sacc[sub][nt], 0, 0, 0);
      }
    }

    // ---- scale + exp + P -> LDS ----
#pragma unroll
    for (int sub = 0; sub < 2; ++sub)
#pragma unroll
      for (int nt = 0; nt < 4; ++nt)
#pragma unroll
        for (int r = 0; r < 4; ++r) {
          float p = __expf(sacc[sub][nt][r] * sr[sub][r]);
          lsum[sub][r] += p;
          Ps[w][swz(sub * 16 + lg * 4 + r, nt * 16 + l15)] = f2bf(p);
        }
    asm volatile("s_waitcnt lgkmcnt(0)");
    __builtin_amdgcn_sched_barrier(0);

    // ---- PV ----
    short8v pa[2][2];
#pragma unroll
    for (int sub = 0; sub < 2; ++sub) {
      pa[sub][0] = *reinterpret_cast<const short8v*>(&Ps[w][swz(sub * 16 + l15, lg * 8)]);
      pa[sub][1] = *reinterpret_cast<const short8v*>(&Ps[w][swz(sub * 16 + l15, 32 + lg * 8)]);
    }
#pragma unroll
    for (int dt = 0; dt < 4; ++dt) {
      short8v vb0 = *reinterpret_cast<const short8v*>(&Vs[cur][swz(dt * 16 + l15, lg * 8)]);
      short8v vb1 = *reinterpret_cast<const short8v*>(&Vs[cur][swz(dt * 16 + l15, 32 + lg * 8)]);
#pragma unroll
      for (int sub = 0; sub < 2; ++sub) {
        oacc[sub][dt] = __builtin_amdgcn_mfma_f32_16x16x32_bf16(pa[sub][0], vb0, oacc[sub][dt], 0, 0, 0);
        oacc[sub][dt] = __builtin_amdgcn_mfma_f32_16x16x32_bf16(pa[sub][1], vb1, oacc[sub][dt], 0, 0, 0);
      }
    }
    __syncthreads();
    if (kt < 31) {
      stage_write(cur ^ 1);
      __syncthreads();
    }
  }

  // softmax denominator: reduce over the 16 lanes sharing each q-row
#pragma unroll
  for (int sub = 0; sub < 2; ++sub)
#pragma unroll
    for (int r = 0; r < 4; ++r) {
#pragma unroll
      for (int o = 8; o; o >>= 1) lsum[sub][r] += __shfl_xor(lsum[sub][r], o);
    }

#pragma unroll
  for (int sub = 0; sub < 2; ++sub)
#pragma unroll
    for (int r = 0; r < 4; ++r) {
      const float inv = 1.0f / lsum[sub][r];
      const int q = q0 + sub * 16 + lg * 4 + r;
#pragma unroll
      for (int dt = 0; dt < 4; ++dt)
        AO[(size_t)(b * L_ + q) * C_ + h * HD_ + dt * 16 + l15] = oacc[sub][dt][r] * inv;
    }
}

// ---------------------------------------------------------------------------
// LayerNorm(C) + ELU + residual + transpose back to [B][C][L]
// ---------------------------------------------------------------------------
__global__ __launch_bounds__(256) void k_ln(const float* __restrict__ PO,
                                            const float* __restrict__ x,
                                            const float* __restrict__ g,
                                            const float* __restrict__ bta,
                                            float* __restrict__ out) {
  __shared__ float buf[32][257];
  __shared__ float mu_s[32], rs_s[32];
  __shared__ float gs[256], bs[256];
  const int b  = blockIdx.y;
  const int l0 = blockIdx.x * 32;
  const int tid = threadIdx.x;
  gs[tid] = g[tid];
  bs[tid] = bta[tid];
#pragma unroll 8
  for (int r = 0; r < 32; ++r)
    buf[r][tid] = PO[((size_t)b * L_ + l0 + r) * C_ + tid];
  __syncthreads();
  {
    const int r  = tid >> 3;
    const int c0 = tid & 7;
    float s1 = 0.f;
#pragma unroll
    for (int i = 0; i < 32; ++i) s1 += buf[r][c0 + (i << 3)];
#pragma unroll
    for (int o = 4; o; o >>= 1) s1 += __shfl_xor(s1, o);
    float mu = s1 * (1.0f / 256.0f);
    float s2 = 0.f;
#pragma unroll
    for (int i = 0; i < 32; ++i) {
      float dv = buf[r][c0 + (i << 3)] - mu;
      s2 += dv * dv;
    }
#pragma unroll
    for (int o = 4; o; o >>= 1) s2 += __shfl_xor(s2, o);
    if (c0 == 0) {
      mu_s[r] = mu;
      rs_s[r] = rsqrtf(s2 * (1.0f / 256.0f) + 1e-5f);
    }
  }
  __syncthreads();
  const int tl = tid & 31;
  const int tc = tid >> 5;
  const float mu = mu_s[tl];
  const float rs = rs_s[tl];
#pragma unroll 8
  for (int c = tc; c < 256; c += 8) {
    float y = (buf[tl][c] - mu) * rs * gs[c] + bs[c];
    float e = (y > 0.f) ? y : (__expf(y) - 1.0f);
    size_t idx = ((size_t)b * C_ + c) * L_ + l0 + tl;
    out[idx] = e + x[idx];
  }
}

// ---------------------------------------------------------------------------
extern "C" void kernel_launch(void* const* d_in, const int* in_sizes, int n_in,
                              void* d_out, int out_size, void* d_ws, size_t ws_size,
                              hipStream_t stream) {
  const float* x_in = (const float*)d_in[0];
  const float* q_w1 = (const float*)d_in[1];
  const float* q_b1 = (const float*)d_in[2];
  const float* q_w2 = (const float*)d_in[3];
  const float* q_b2 = (const float*)d_in[4];
  const float* k_w1 = (const float*)d_in[5];
  const float* k_b1 = (const float*)d_in[6];
  const float* k_w2 = (const float*)d_in[7];
  const float* k_b2 = (const float*)d_in[8];
  const float* v_w1 = (const float*)d_in[9];
  const float* v_b1 = (const float*)d_in[10];
  const float* v_w2 = (const float*)d_in[11];
  const float* v_b2 = (const float*)d_in[12];
  const float* o_w  = (const float*)d_in[13];
  const float* o_b  = (const float*)d_in[14];
  const float* ln_g = (const float*)d_in[15];
  const float* ln_b = (const float*)d_in[16];
  float* out = (float*)d_out;
  float* ws  = (float*)d_ws;

  const size_t NB = (size_t)B_ * L_ * C_;          // 4,194,304 floats
  float* Xr = ws;                                  // [B*L][C]; later Vb
  float* Hb = ws + NB;                             // MLP hidden; later Qh/Kh (bf16)
  float* Qb = ws + 2 * NB;                         // Q fp32; later PO
  float* Kb = ws + 3 * NB;                         // K fp32; later AO
  float* Gp = ws + 4 * NB;                         // 32*8*4096
  float* G  = Gp + (size_t)32 * 8 * 4096;          // 32*4096
  float* Scl = G + (size_t)32 * 4096;              // 32*2048
  short* Vt  = (short*)(Scl + (size_t)32 * 2048);  // bf16 [32][64][2048]
  float* Vb = Xr;
  short* Qh = (short*)Hb;                          // bf16 [32][2048][64]
  short* Kh = (short*)(Hb + NB / 2);
  float* AO = Kb;
  float* PO = Qb;

  dim3 ggrid(B_ * L_ / 128, C_ / 128);

  k_transpose<<<dim3(L_ / 32, C_ / 32, B_), dim3(32, 8), 0, stream>>>(x_in, Xr);

  k_gemm<<<ggrid, 256, 0, stream>>>(Xr, q_w1, q_b1, Hb, 1);
  k_gemm<<<ggrid, 256, 0, stream>>>(Hb, q_w2, q_b2, Qb, 0);
  k_gemm<<<ggrid, 256, 0, stream>>>(Xr, k_w1, k_b1, Hb, 1);
  k_gemm<<<ggrid, 256, 0, stream>>>(Hb, k_w2, k_b2, Kb, 0);
  k_gemm<<<ggrid, 256, 0, stream>>>(Xr, v_w1, v_b1, Hb, 1);
  k_gemm<<<ggrid, 256, 0, stream>>>(Hb, v_w2, v_b2, Vb, 0);   // Vb aliases Xr; Hb free after

  k_gram<<<dim3(8, H_, B_), 256, 0, stream>>>(Kb, Gp);
  k_gram_reduce<<<dim3(32), 256, 0, stream>>>(Gp, G);
  k_scale<<<dim3(L_ / 64, H_, B_), 256, 0, stream>>>(Qb, G, Scl);

  k_pack_qk<<<dim3(B_ * L_ / 64), 256, 0, stream>>>(Qb, Kb, Qh, Kh);
  k_packt_v<<<dim3(L_ / 64, H_, B_), 256, 0, stream>>>(Vb, Vt);

  k_attn_mfma<<<dim3(L_ / 128, H_, B_), 256, 0, stream>>>(Qh, Kh, Vt, Scl, AO);

  k_gemm<<<ggrid, 256, 0, stream>>>(AO, o_w, o_b, PO, 0);     // PO aliases Qb

  k_ln<<<dim3(L_ / 32, B_), 256, 0, stream>>>(PO, x_in, ln_g, ln_b, out);
}

// Round 4
// 318.334 us; speedup vs baseline: 2.9220x; 1.5200x over previous
//
#include <hip/hip_runtime.h>
#include <hip/hip_bf16.h>
#include <cstdint>
#include <cstddef>

#define B_  8
#define C_  256
#define L_  2048
#define H_  4
#define HD_ 64

using short8v = __attribute__((ext_vector_type(8))) short;
using f32x4   = __attribute__((ext_vector_type(4))) float;

// ---------------------------------------------------------------------------
// helpers
// ---------------------------------------------------------------------------
__device__ __forceinline__ float gelu_exact(float v) {
  return 0.5f * v * (1.0f + erff(v * 0.70710678118654752440f));
}

__device__ __forceinline__ short f2bf(float v) {
  __hip_bfloat16 h = __float2bfloat16(v);
  return *reinterpret_cast<short*>(&h);
}

__device__ __forceinline__ float bf2f(short s) {
  __hip_bfloat16 h = *reinterpret_cast<__hip_bfloat16*>(&s);
  return __bfloat162float(h);
}

__device__ __forceinline__ void fma16(float (&acc)[4][4], const float4 a, const float4 b) {
  acc[0][0] += a.x * b.x; acc[0][1] += a.x * b.y; acc[0][2] += a.x * b.z; acc[0][3] += a.x * b.w;
  acc[1][0] += a.y * b.x; acc[1][1] += a.y * b.y; acc[1][2] += a.y * b.z; acc[1][3] += a.y * b.w;
  acc[2][0] += a.z * b.x; acc[2][1] += a.z * b.y; acc[2][2] += a.z * b.z; acc[2][3] += a.z * b.w;
  acc[3][0] += a.w * b.x; acc[3][1] += a.w * b.y; acc[3][2] += a.w * b.z; acc[3][3] += a.w * b.w;
}

// ---------------------------------------------------------------------------
// transpose: x[B][C][L] -> Xr[B][L][C]
// ---------------------------------------------------------------------------
__global__ __launch_bounds__(256) void k_transpose(const float* __restrict__ x,
                                                   float* __restrict__ Xr) {
  __shared__ float t[32][33];
  const int l0 = blockIdx.x * 32;
  const int c0 = blockIdx.y * 32;
  const int b  = blockIdx.z;
  const int tx = threadIdx.x;   // 0..31
  const int ty = threadIdx.y;   // 0..7
  const float* xp  = x  + (size_t)b * C_ * L_;
  float*       xrp = Xr + (size_t)b * L_ * C_;
#pragma unroll
  for (int i = 0; i < 32; i += 8)
    t[ty + i][tx] = xp[(size_t)(c0 + ty + i) * L_ + (l0 + tx)];
  __syncthreads();
#pragma unroll
  for (int i = 0; i < 32; i += 8)
    xrp[(size_t)(l0 + ty + i) * C_ + (c0 + tx)] = t[tx][ty + i];
}

// ---------------------------------------------------------------------------
// weight pack: W[256][256] fp32 -> Wt_hi/Wt_lo bf16 [n][k] (transposed+split)
// grid (8, 8, 7), block 256
// ---------------------------------------------------------------------------
__global__ __launch_bounds__(256) void k_packw(
    const float* __restrict__ w0, const float* __restrict__ w1,
    const float* __restrict__ w2, const float* __restrict__ w3,
    const float* __restrict__ w4, const float* __restrict__ w5,
    const float* __restrict__ w6,
    short* __restrict__ hi, short* __restrict__ lo) {
  const float* Ws[7] = {w0, w1, w2, w3, w4, w5, w6};
  const int wi = blockIdx.z;
  const float* W = Ws[wi];
  __shared__ float T[32][33];
  const int k0 = blockIdx.x * 32, n0 = blockIdx.y * 32;
  const int tx = threadIdx.x & 31, ty = threadIdx.x >> 5;  // 32 x 8
#pragma unroll
  for (int i = 0; i < 32; i += 8)
    T[ty + i][tx] = W[(size_t)(k0 + ty + i) * 256 + n0 + tx];   // T[k][n]
  __syncthreads();
  short* ho = hi + (size_t)wi * 65536;
  short* lp = lo + (size_t)wi * 65536;
#pragma unroll
  for (int i = 0; i < 32; i += 8) {
    float v = T[tx][ty + i];            // k = k0+tx, n = n0+ty+i
    short h = f2bf(v);
    float r = v - bf2f(h);
    ho[(size_t)(n0 + ty + i) * 256 + k0 + tx] = h;
    lp[(size_t)(n0 + ty + i) * 256 + k0 + tx] = f2bf(r);
  }
}

// ---------------------------------------------------------------------------
// split-bf16 MFMA GEMM: Cout[M,256] = act(A[M,256] @ W + bias)
// A fp32, split on the fly; W pre-split (Wth/Wtl, [n][k]).
// C = Ah*Wh + Ah*Wl + Al*Wh  (fp32 MFMA accum) ~= fp32 GEMM.
// tile 64(M) x 128(N), BK=32, 256 threads / 4 waves, wave tile 32x64.
// LDS tiles [row][k] with 16B-granule XOR swizzle: g' = g ^ (row & 3).
// ---------------------------------------------------------------------------
__global__ __launch_bounds__(256, 3) void k_gemm_s(
    const float* __restrict__ A, const short* __restrict__ Wth,
    const short* __restrict__ Wtl, const float* __restrict__ bias,
    float* __restrict__ Cout, int actGelu) {
  __shared__ short Ah[2][64 * 32], Al[2][64 * 32];
  __shared__ short Bh[2][128 * 32], Bl[2][128 * 32];
  const int tid  = threadIdx.x;
  const int lane = tid & 63;
  const int w    = tid >> 6;
  const int wm = w & 1, wn = w >> 1;
  const int m0 = blockIdx.x * 64;
  const int n0 = blockIdx.y * 128;
  const int l15 = lane & 15, lg = lane >> 4;

  const int ar  = tid >> 2;        // A row 0..63
  const int ag  = tid & 3;         // A k-granule (8 f32)
  const int br  = tid >> 1;        // B row (n) 0..127
  const int bg0 = (tid & 1) * 2;   // B k-granules {bg0, bg0+1}

  float4 fA0, fA1;
  short8v rBh0, rBh1, rBl0, rBl1;
  auto gload = [&](int ks) {
    const float* ap = &A[(size_t)(m0 + ar) * 256 + ks * 32 + ag * 8];
    fA0 = *reinterpret_cast<const float4*>(ap);
    fA1 = *reinterpret_cast<const float4*>(ap + 4);
    const short* bph = &Wth[(size_t)(n0 + br) * 256 + ks * 32 + bg0 * 8];
    const short* bpl = &Wtl[(size_t)(n0 + br) * 256 + ks * 32 + bg0 * 8];
    rBh0 = *reinterpret_cast<const short8v*>(bph);
    rBh1 = *reinterpret_cast<const short8v*>(bph + 8);
    rBl0 = *reinterpret_cast<const short8v*>(bpl);
    rBl1 = *reinterpret_cast<const short8v*>(bpl + 8);
  };
  auto lwrite = [&](int buf) {
    float av[8] = {fA0.x, fA0.y, fA0.z, fA0.w, fA1.x, fA1.y, fA1.z, fA1.w};
    short8v h8, l8;
#pragma unroll
    for (int i = 0; i < 8; ++i) {
      short h = f2bf(av[i]);
      h8[i] = h;
      l8[i] = f2bf(av[i] - bf2f(h));
    }
    const int gA = ag ^ (ar & 3);
    *reinterpret_cast<short8v*>(&Ah[buf][ar * 32 + gA * 8]) = h8;
    *reinterpret_cast<short8v*>(&Al[buf][ar * 32 + gA * 8]) = l8;
    const int g0 = bg0 ^ (br & 3);
    const int g1 = (bg0 + 1) ^ (br & 3);
    *reinterpret_cast<short8v*>(&Bh[buf][br * 32 + g0 * 8]) = rBh0;
    *reinterpret_cast<short8v*>(&Bh[buf][br * 32 + g1 * 8]) = rBh1;
    *reinterpret_cast<short8v*>(&Bl[buf][br * 32 + g0 * 8]) = rBl0;
    *reinterpret_cast<short8v*>(&Bl[buf][br * 32 + g1 * 8]) = rBl1;
  };

  const f32x4 z4 = {0.f, 0.f, 0.f, 0.f};
  f32x4 acc[2][4];
#pragma unroll
  for (int s = 0; s < 2; ++s)
#pragma unroll
    for (int nt = 0; nt < 4; ++nt) acc[s][nt] = z4;

  gload(0);
  lwrite(0);
  __syncthreads();

  for (int ks = 0; ks < 8; ++ks) {
    const int cur = ks & 1;
    if (ks < 7) gload(ks + 1);
    short8v a_h[2], a_l[2];
#pragma unroll
    for (int s = 0; s < 2; ++s) {
      const int m = wm * 32 + s * 16 + l15;
      const int g = lg ^ (m & 3);
      a_h[s] = *reinterpret_cast<const short8v*>(&Ah[cur][m * 32 + g * 8]);
      a_l[s] = *reinterpret_cast<const short8v*>(&Al[cur][m * 32 + g * 8]);
    }
#pragma unroll
    for (int nt = 0; nt < 4; ++nt) {
      const int n = wn * 64 + nt * 16 + l15;
      const int g = lg ^ (n & 3);
      short8v b_h = *reinterpret_cast<const short8v*>(&Bh[cur][n * 32 + g * 8]);
      short8v b_l = *reinterpret_cast<const short8v*>(&Bl[cur][n * 32 + g * 8]);
#pragma unroll
      for (int s = 0; s < 2; ++s) {
        acc[s][nt] = __builtin_amdgcn_mfma_f32_16x16x32_bf16(a_h[s], b_h, acc[s][nt], 0, 0, 0);
        acc[s][nt] = __builtin_amdgcn_mfma_f32_16x16x32_bf16(a_h[s], b_l, acc[s][nt], 0, 0, 0);
        acc[s][nt] = __builtin_amdgcn_mfma_f32_16x16x32_bf16(a_l[s], b_h, acc[s][nt], 0, 0, 0);
      }
    }
    if (ks < 7) lwrite(cur ^ 1);
    __syncthreads();
  }

  // epilogue: bias (+GELU), fp32 store. C row = m0+wm*32+s*16+lg*4+r, col = n0+wn*64+nt*16+l15
#pragma unroll
  for (int nt = 0; nt < 4; ++nt) {
    const int col = n0 + wn * 64 + nt * 16 + l15;
    const float bv = bias[col];
#pragma unroll
    for (int s = 0; s < 2; ++s)
#pragma unroll
      for (int r = 0; r < 4; ++r) {
        const int row = m0 + wm * 32 + s * 16 + lg * 4 + r;
        float v = acc[s][nt][r] + bv;
        if (actGelu) v = gelu_exact(v);
        Cout[(size_t)row * 256 + col] = v;
      }
  }
}

// ---------------------------------------------------------------------------
// Gram partials: Gp[bh][chunk] = K_chunk^T @ K_chunk (64x64), fp32
// ---------------------------------------------------------------------------
__global__ __launch_bounds__(256) void k_gram(const float* __restrict__ Kg,
                                              float* __restrict__ Gp) {
  __shared__ float Ks[64][68];
  const int tid = threadIdx.x;
  const int tm = tid >> 4;
  const int tn = tid & 15;
  const int chunk = blockIdx.x;
  const int h = blockIdx.y;
  const int b = blockIdx.z;
  const size_t base = (size_t)b * L_ * C_ + (size_t)h * HD_ + (size_t)chunk * 256 * C_;
  const int lr = tid >> 2;
  const int lf = tid & 3;
  float acc[4][4] = {};
  for (int st = 0; st < 4; ++st) {
    __syncthreads();
#pragma unroll
    for (int i = 0; i < 4; ++i) {
      int fg = lf * 4 + i;
      float4 v = *reinterpret_cast<const float4*>(&Kg[base + (size_t)(st * 64 + lr) * C_ + fg * 4]);
      *reinterpret_cast<float4*>(&Ks[lr][fg * 4]) = v;
    }
    __syncthreads();
#pragma unroll 16
    for (int r = 0; r < 64; ++r) {
      float4 a  = *reinterpret_cast<const float4*>(&Ks[r][tm << 2]);
      float4 b2 = *reinterpret_cast<const float4*>(&Ks[r][tn << 2]);
      fma16(acc, a, b2);
    }
  }
  const int bh = b * H_ + h;
  float* gp = Gp + ((size_t)bh * 8 + chunk) * 4096;
#pragma unroll
  for (int i = 0; i < 4; ++i)
    *reinterpret_cast<float4*>(&gp[((tm << 2) + i) * 64 + (tn << 2)]) =
        make_float4(acc[i][0], acc[i][1], acc[i][2], acc[i][3]);
}

__global__ __launch_bounds__(256) void k_gram_reduce(const float* __restrict__ Gp,
                                                     float* __restrict__ G) {
  const int bh = blockIdx.x;
  const int tid = threadIdx.x;
  for (int t = tid; t < 4096; t += 256) {
    float s = 0.f;
#pragma unroll
    for (int c = 0; c < 8; ++c) s += Gp[((size_t)bh * 8 + c) * 4096 + t];
    G[(size_t)bh * 4096 + t] = s;
  }
}

// ---------------------------------------------------------------------------
// per-row Lipschitz scale: Scl[bh][l] = 1 / (sqrt(q^T G q) + 8e-12)
// ---------------------------------------------------------------------------
__global__ __launch_bounds__(256) void k_scale(const float* __restrict__ Qg,
                                               const float* __restrict__ Gm,
                                               float* __restrict__ Scl) {
  __shared__ float QsT[64][68];
  __shared__ float Gs[64][68];
  const int tid = threadIdx.x;
  const int tm = tid >> 4;
  const int tn = tid & 15;
  const int q0 = blockIdx.x * 64;
  const int h  = blockIdx.y;
  const int b  = blockIdx.z;
  const int bh = b * H_ + h;
  const size_t base = (size_t)b * L_ * C_ + (size_t)h * HD_;
  const int lr = tid >> 2;
  const int lf = tid & 3;
#pragma unroll
  for (int i = 0; i < 4; ++i) {
    int fg = lf * 4 + i;
    float4 v = *reinterpret_cast<const float4*>(&Qg[base + (size_t)(q0 + lr) * C_ + fg * 4]);
    QsT[fg * 4 + 0][lr] = v.x;
    QsT[fg * 4 + 1][lr] = v.y;
    QsT[fg * 4 + 2][lr] = v.z;
    QsT[fg * 4 + 3][lr] = v.w;
    float4 g = *reinterpret_cast<const float4*>(&Gm[(size_t)bh * 4096 + lr * 64 + fg * 4]);
    *reinterpret_cast<float4*>(&Gs[lr][fg * 4]) = g;
  }
  __syncthreads();
  float t4[4][4] = {};
#pragma unroll 16
  for (int e = 0; e < 64; ++e) {
    float4 a  = *reinterpret_cast<const float4*>(&QsT[e][tm << 2]);
    float4 b2 = *reinterpret_cast<const float4*>(&Gs[e][tn << 2]);
    fma16(t4, a, b2);
  }
  float r2[4];
#pragma unroll
  for (int i = 0; i < 4; ++i) {
    r2[i] = t4[i][0] * QsT[(tn << 2) + 0][(tm << 2) + i]
          + t4[i][1] * QsT[(tn << 2) + 1][(tm << 2) + i]
          + t4[i][2] * QsT[(tn << 2) + 2][(tm << 2) + i]
          + t4[i][3] * QsT[(tn << 2) + 3][(tm << 2) + i];
#pragma unroll
    for (int o = 8; o; o >>= 1) r2[i] += __shfl_xor(r2[i], o);
  }
  if (tn == 0) {
#pragma unroll
    for (int i = 0; i < 4; ++i) {
      float rr = fmaxf(r2[i], 0.f);
      Scl[(size_t)bh * L_ + q0 + (tm << 2) + i] = 1.0f / (sqrtf(rr) + 8e-12f);
    }
  }
}

// ---------------------------------------------------------------------------
// pack Q,K fp32 [B*L][C] -> bf16 [BH][L][64]
// ---------------------------------------------------------------------------
__global__ __launch_bounds__(256) void k_pack_qk(const float* __restrict__ Qf,
                                                 const float* __restrict__ Kf,
                                                 short* __restrict__ Qh,
                                                 short* __restrict__ Kh) {
  const int blk = blockIdx.x;
  const int tid = threadIdx.x;
#pragma unroll
  for (int i = 0; i < 16; ++i) {
    int idx = tid + 256 * i;
    int row = idx >> 6;
    int c4  = idx & 63;
    int R = blk * 64 + row;
    int b = R >> 11, l = R & 2047;
    int h = c4 >> 4, d4 = c4 & 15;
    size_t o = ((size_t)(b * H_ + h) * L_ + l) * HD_ + d4 * 4;
    float4 q = *reinterpret_cast<const float4*>(&Qf[(size_t)R * C_ + c4 * 4]);
    float4 k = *reinterpret_cast<const float4*>(&Kf[(size_t)R * C_ + c4 * 4]);
    short4 qs, ks;
    qs.x = f2bf(q.x); qs.y = f2bf(q.y); qs.z = f2bf(q.z); qs.w = f2bf(q.w);
    ks.x = f2bf(k.x); ks.y = f2bf(k.y); ks.z = f2bf(k.z); ks.w = f2bf(k.w);
    *reinterpret_cast<short4*>(&Qh[o]) = qs;
    *reinterpret_cast<short4*>(&Kh[o]) = ks;
  }
}

// ---------------------------------------------------------------------------
// pack+transpose V fp32 [B*L][C] -> bf16 Vt[BH][64 d][L]
// ---------------------------------------------------------------------------
__global__ __launch_bounds__(256) void k_packt_v(const float* __restrict__ Vf,
                                                 short* __restrict__ Vt) {
  __shared__ float T[64][65];
  const int lt = blockIdx.x;
  const int h = blockIdx.y, b = blockIdx.z;
  const int bh = b * H_ + h;
  const int tid = threadIdx.x;
#pragma unroll
  for (int i = 0; i < 4; ++i) {
    int idx = tid + 256 * i;
    int l = idx >> 4;
    int c4 = idx & 15;
    float4 v = *reinterpret_cast<const float4*>(
        &Vf[(size_t)(b * L_ + lt * 64 + l) * C_ + h * HD_ + c4 * 4]);
    T[l][c4 * 4 + 0] = v.x;
    T[l][c4 * 4 + 1] = v.y;
    T[l][c4 * 4 + 2] = v.z;
    T[l][c4 * 4 + 3] = v.w;
  }
  __syncthreads();
  const int d  = tid >> 2;
  const int ls = (tid & 3) * 16;
#pragma unroll
  for (int i = 0; i < 4; ++i) {
    int l = ls + i * 4;
    short4 s;
    s.x = f2bf(T[l + 0][d]);
    s.y = f2bf(T[l + 1][d]);
    s.z = f2bf(T[l + 2][d]);
    s.w = f2bf(T[l + 3][d]);
    *reinterpret_cast<short4*>(&Vt[((size_t)bh * HD_ + d) * L_ + lt * 64 + l]) = s;
  }
}

// ---------------------------------------------------------------------------
// MFMA attention (unchanged from round 3 — verified passing)
// ---------------------------------------------------------------------------
__device__ __forceinline__ int swz(int r, int c) {
  return (r * 64 + c) ^ ((r & 7) << 3);
}

__global__ __launch_bounds__(256) void k_attn_mfma(
    const short* __restrict__ Qh, const short* __restrict__ Kh,
    const short* __restrict__ Vt, const float* __restrict__ Scl,
    float* __restrict__ AO) {
  __shared__ short Ks[2][64 * 64];
  __shared__ short Vs[2][64 * 64];
  __shared__ short Ps[4][32 * 64];
  const int tid  = threadIdx.x;
  const int lane = tid & 63;
  const int w    = tid >> 6;
  const int h = blockIdx.y, b = blockIdx.z;
  const int bh = b * H_ + h;
  const size_t hb = (size_t)bh * L_ * HD_;
  const int q0 = blockIdx.x * 128 + w * 32;
  const int l15 = lane & 15;
  const int lg  = lane >> 4;
  const int srow = tid >> 3;
  const int sseg = tid & 7;

  short8v aq[2][2];
#pragma unroll
  for (int sub = 0; sub < 2; ++sub)
#pragma unroll
    for (int ch = 0; ch < 2; ++ch)
      aq[sub][ch] = *reinterpret_cast<const short8v*>(
          &Qh[hb + (size_t)(q0 + sub * 16 + l15) * HD_ + ch * 32 + lg * 8]);

  float sr[2][4];
#pragma unroll
  for (int sub = 0; sub < 2; ++sub)
#pragma unroll
    for (int r = 0; r < 4; ++r)
      sr[sub][r] = Scl[(size_t)bh * L_ + q0 + sub * 16 + lg * 4 + r];

  short8v stK0, stK1, stV0, stV1;
  auto stage_load = [&](int kt) {
    stK0 = *reinterpret_cast<const short8v*>(&Kh[hb + (size_t)(kt * 64 + srow) * HD_ + sseg * 8]);
    stK1 = *reinterpret_cast<const short8v*>(&Kh[hb + (size_t)(kt * 64 + 32 + srow) * HD_ + sseg * 8]);
    stV0 = *reinterpret_cast<const short8v*>(&Vt[hb + (size_t)srow * L_ + kt * 64 + sseg * 8]);
    stV1 = *reinterpret_cast<const short8v*>(&Vt[hb + (size_t)(32 + srow) * L_ + kt * 64 + sseg * 8]);
  };
  auto stage_write = [&](int buf) {
    *reinterpret_cast<short8v*>(&Ks[buf][swz(srow, sseg * 8)]) = stK0;
    *reinterpret_cast<short8v*>(&Ks[buf][swz(32 + srow, sseg * 8)]) = stK1;
    *reinterpret_cast<short8v*>(&Vs[buf][swz(srow, sseg * 8)]) = stV0;
    *reinterpret_cast<short8v*>(&Vs[buf][swz(32 + srow, sseg * 8)]) = stV1;
  };

  const f32x4 z4 = {0.f, 0.f, 0.f, 0.f};
  float lsum[2][4] = {};
  f32x4 oacc[2][4];
#pragma unroll
  for (int s = 0; s < 2; ++s)
#pragma unroll
    for (int d = 0; d < 4; ++d) oacc[s][d] = z4;

  stage_load(0);
  stage_write(0);
  __syncthreads();

  for (int kt = 0; kt < 32; ++kt) {
    const int cur = kt & 1;
    if (kt < 31) stage_load(kt + 1);

    f32x4 sacc[2][4];
#pragma unroll
    for (int s = 0; s < 2; ++s)
#pragma unroll
      for (int nt = 0; nt < 4; ++nt) sacc[s][nt] = z4;
#pragma unroll
    for (int nt = 0; nt < 4; ++nt) {
      short8v kb0 = *reinterpret_cast<const short8v*>(&Ks[cur][swz(nt * 16 + l15, lg * 8)]);
      short8v kb1 = *reinterpret_cast<const short8v*>(&Ks[cur][swz(nt * 16 + l15, 32 + lg * 8)]);
#pragma unroll
      for (int sub = 0; sub < 2; ++sub) {
        sacc[sub][nt] = __builtin_amdgcn_mfma_f32_16x16x32_bf16(aq[sub][0], kb0, sacc[sub][nt], 0, 0, 0);
        sacc[sub][nt] = __builtin_amdgcn_mfma_f32_16x16x32_bf16(aq[sub][1], kb1, sacc[sub][nt], 0, 0, 0);
      }
    }

#pragma unroll
    for (int sub = 0; sub < 2; ++sub)
#pragma unroll
      for (int nt = 0; nt < 4; ++nt)
#pragma unroll
        for (int r = 0; r < 4; ++r) {
          float p = __expf(sacc[sub][nt][r] * sr[sub][r]);
          lsum[sub][r] += p;
          Ps[w][swz(sub * 16 + lg * 4 + r, nt * 16 + l15)] = f2bf(p);
        }
    asm volatile("s_waitcnt lgkmcnt(0)");
    __builtin_amdgcn_sched_barrier(0);

    short8v pa[2][2];
#pragma unroll
    for (int sub = 0; sub < 2; ++sub) {
      pa[sub][0] = *reinterpret_cast<const short8v*>(&Ps[w][swz(sub * 16 + l15, lg * 8)]);
      pa[sub][1] = *reinterpret_cast<const short8v*>(&Ps[w][swz(sub * 16 + l15, 32 + lg * 8)]);
    }
#pragma unroll
    for (int dt = 0; dt < 4; ++dt) {
      short8v vb0 = *reinterpret_cast<const short8v*>(&Vs[cur][swz(dt * 16 + l15, lg * 8)]);
      short8v vb1 = *reinterpret_cast<const short8v*>(&Vs[cur][swz(dt * 16 + l15, 32 + lg * 8)]);
#pragma unroll
      for (int sub = 0; sub < 2; ++sub) {
        oacc[sub][dt] = __builtin_amdgcn_mfma_f32_16x16x32_bf16(pa[sub][0], vb0, oacc[sub][dt], 0, 0, 0);
        oacc[sub][dt] = __builtin_amdgcn_mfma_f32_16x16x32_bf16(pa[sub][1], vb1, oacc[sub][dt], 0, 0, 0);
      }
    }
    __syncthreads();
    if (kt < 31) {
      stage_write(cur ^ 1);
      __syncthreads();
    }
  }

#pragma unroll
  for (int sub = 0; sub < 2; ++sub)
#pragma unroll
    for (int r = 0; r < 4; ++r) {
#pragma unroll
      for (int o = 8; o; o >>= 1) lsum[sub][r] += __shfl_xor(lsum[sub][r], o);
    }

#pragma unroll
  for (int sub = 0; sub < 2; ++sub)
#pragma unroll
    for (int r = 0; r < 4; ++r) {
      const float inv = 1.0f / lsum[sub][r];
      const int q = q0 + sub * 16 + lg * 4 + r;
#pragma unroll
      for (int dt = 0; dt < 4; ++dt)
        AO[(size_t)(b * L_ + q) * C_ + h * HD_ + dt * 16 + l15] = oacc[sub][dt][r] * inv;
    }
}

// ---------------------------------------------------------------------------
// LayerNorm(C) + ELU + residual + transpose back to [B][C][L]
// ---------------------------------------------------------------------------
__global__ __launch_bounds__(256) void k_ln(const float* __restrict__ PO,
                                            const float* __restrict__ x,
                                            const float* __restrict__ g,
                                            const float* __restrict__ bta,
                                            float* __restrict__ out) {
  __shared__ float buf[32][257];
  __shared__ float mu_s[32], rs_s[32];
  __shared__ float gs[256], bs[256];
  const int b  = blockIdx.y;
  const int l0 = blockIdx.x * 32;
  const int tid = threadIdx.x;
  gs[tid] = g[tid];
  bs[tid] = bta[tid];
#pragma unroll 8
  for (int r = 0; r < 32; ++r)
    buf[r][tid] = PO[((size_t)b * L_ + l0 + r) * C_ + tid];
  __syncthreads();
  {
    const int r  = tid >> 3;
    const int c0 = tid & 7;
    float s1 = 0.f;
#pragma unroll
    for (int i = 0; i < 32; ++i) s1 += buf[r][c0 + (i << 3)];
#pragma unroll
    for (int o = 4; o; o >>= 1) s1 += __shfl_xor(s1, o);
    float mu = s1 * (1.0f / 256.0f);
    float s2 = 0.f;
#pragma unroll
    for (int i = 0; i < 32; ++i) {
      float dv = buf[r][c0 + (i << 3)] - mu;
      s2 += dv * dv;
    }
#pragma unroll
    for (int o = 4; o; o >>= 1) s2 += __shfl_xor(s2, o);
    if (c0 == 0) {
      mu_s[r] = mu;
      rs_s[r] = rsqrtf(s2 * (1.0f / 256.0f) + 1e-5f);
    }
  }
  __syncthreads();
  const int tl = tid & 31;
  const int tc = tid >> 5;
  const float mu = mu_s[tl];
  const float rs = rs_s[tl];
#pragma unroll 8
  for (int c = tc; c < 256; c += 8) {
    float y = (buf[tl][c] - mu) * rs * gs[c] + bs[c];
    float e = (y > 0.f) ? y : (__expf(y) - 1.0f);
    size_t idx = ((size_t)b * C_ + c) * L_ + l0 + tl;
    out[idx] = e + x[idx];
  }
}

// ---------------------------------------------------------------------------
extern "C" void kernel_launch(void* const* d_in, const int* in_sizes, int n_in,
                              void* d_out, int out_size, void* d_ws, size_t ws_size,
                              hipStream_t stream) {
  const float* x_in = (const float*)d_in[0];
  const float* q_w1 = (const float*)d_in[1];
  const float* q_b1 = (const float*)d_in[2];
  const float* q_w2 = (const float*)d_in[3];
  const float* q_b2 = (const float*)d_in[4];
  const float* k_w1 = (const float*)d_in[5];
  const float* k_b1 = (const float*)d_in[6];
  const float* k_w2 = (const float*)d_in[7];
  const float* k_b2 = (const float*)d_in[8];
  const float* v_w1 = (const float*)d_in[9];
  const float* v_b1 = (const float*)d_in[10];
  const float* v_w2 = (const float*)d_in[11];
  const float* v_b2 = (const float*)d_in[12];
  const float* o_w  = (const float*)d_in[13];
  const float* o_b  = (const float*)d_in[14];
  const float* ln_g = (const float*)d_in[15];
  const float* ln_b = (const float*)d_in[16];
  float* out = (float*)d_out;
  float* ws  = (float*)d_ws;

  const size_t NB = (size_t)B_ * L_ * C_;          // 4,194,304 floats
  float* Xr = ws;                                  // [B*L][C]; later Vb
  float* Hb = ws + NB;                             // MLP hidden; later Qh/Kh (bf16)
  float* Qb = ws + 2 * NB;                         // Q fp32; later PO
  float* Kb = ws + 3 * NB;                         // K fp32; later AO
  float* Gp = ws + 4 * NB;                         // 32*8*4096
  float* G  = Gp + (size_t)32 * 8 * 4096;          // 32*4096
  float* Scl = G + (size_t)32 * 4096;              // 32*2048
  short* Vt  = (short*)(Scl + (size_t)32 * 2048);  // bf16 [32][64][2048] (8MB)
  short* Whi = Vt + (size_t)32 * HD_ * L_;         // 7*65536 shorts
  short* Wlo = Whi + (size_t)7 * 65536;            // 7*65536 shorts
  float* Vb = Xr;
  short* Qh = (short*)Hb;
  short* Kh = (short*)(Hb + NB / 2);
  float* AO = Kb;
  float* PO = Qb;

  dim3 ggrid(B_ * L_ / 64, C_ / 128);   // (256, 2) = 512 blocks

  k_packw<<<dim3(8, 8, 7), 256, 0, stream>>>(q_w1, q_w2, k_w1, k_w2, v_w1, v_w2, o_w, Whi, Wlo);
  k_transpose<<<dim3(L_ / 32, C_ / 32, B_), dim3(32, 8), 0, stream>>>(x_in, Xr);

  const size_t WN = 65536;
  k_gemm_s<<<ggrid, 256, 0, stream>>>(Xr, Whi + 0 * WN, Wlo + 0 * WN, q_b1, Hb, 1);
  k_gemm_s<<<ggrid, 256, 0, stream>>>(Hb, Whi + 1 * WN, Wlo + 1 * WN, q_b2, Qb, 0);
  k_gemm_s<<<ggrid, 256, 0, stream>>>(Xr, Whi + 2 * WN, Wlo + 2 * WN, k_b1, Hb, 1);
  k_gemm_s<<<ggrid, 256, 0, stream>>>(Hb, Whi + 3 * WN, Wlo + 3 * WN, k_b2, Kb, 0);
  k_gemm_s<<<ggrid, 256, 0, stream>>>(Xr, Whi + 4 * WN, Wlo + 4 * WN, v_b1, Hb, 1);
  k_gemm_s<<<ggrid, 256, 0, stream>>>(Hb, Whi + 5 * WN, Wlo + 5 * WN, v_b2, Vb, 0);  // Vb aliases Xr

  k_gram<<<dim3(8, H_, B_), 256, 0, stream>>>(Kb, Gp);
  k_gram_reduce<<<dim3(32), 256, 0, stream>>>(Gp, G);
  k_scale<<<dim3(L_ / 64, H_, B_), 256, 0, stream>>>(Qb, G, Scl);

  k_pack_qk<<<dim3(B_ * L_ / 64), 256, 0, stream>>>(Qb, Kb, Qh, Kh);
  k_packt_v<<<dim3(L_ / 64, H_, B_), 256, 0, stream>>>(Vb, Vt);

  k_attn_mfma<<<dim3(L_ / 128, H_, B_), 256, 0, stream>>>(Qh, Kh, Vt, Scl, AO);

  k_gemm_s<<<ggrid, 256, 0, stream>>>(AO, Whi + 6 * WN, Wlo + 6 * WN, o_b, PO, 0);  // PO aliases Qb

  k_ln<<<dim3(L_ / 32, B_), 256, 0, stream>>>(PO, x_in, ln_g, ln_b, out);
}

// Round 5
// 304.453 us; speedup vs baseline: 3.0552x; 1.0456x over previous
//
#include <hip/hip_runtime.h>
#include <hip/hip_bf16.h>
#include <cstdint>
#include <cstddef>

#define B_  8
#define C_  256
#define L_  2048
#define H_  4
#define HD_ 64

using short8v = __attribute__((ext_vector_type(8))) short;
using f32x4   = __attribute__((ext_vector_type(4))) float;

// ---------------------------------------------------------------------------
// helpers
// ---------------------------------------------------------------------------
__device__ __forceinline__ float gelu_exact(float v) {
  return 0.5f * v * (1.0f + erff(v * 0.70710678118654752440f));
}

__device__ __forceinline__ short f2bf(float v) {
  __hip_bfloat16 h = __float2bfloat16(v);
  return *reinterpret_cast<short*>(&h);
}

__device__ __forceinline__ float bf2f(short s) {
  __hip_bfloat16 h = *reinterpret_cast<__hip_bfloat16*>(&s);
  return __bfloat162float(h);
}

__device__ __forceinline__ void fma16(float (&acc)[4][4], const float4 a, const float4 b) {
  acc[0][0] += a.x * b.x; acc[0][1] += a.x * b.y; acc[0][2] += a.x * b.z; acc[0][3] += a.x * b.w;
  acc[1][0] += a.y * b.x; acc[1][1] += a.y * b.y; acc[1][2] += a.y * b.z; acc[1][3] += a.y * b.w;
  acc[2][0] += a.z * b.x; acc[2][1] += a.z * b.y; acc[2][2] += a.z * b.z; acc[2][3] += a.z * b.w;
  acc[3][0] += a.w * b.x; acc[3][1] += a.w * b.y; acc[3][2] += a.w * b.z; acc[3][3] += a.w * b.w;
}

// ---------------------------------------------------------------------------
// transpose + split: x[B][C][L] fp32 -> Xh/Xl bf16 planes [B*L][C]
// ---------------------------------------------------------------------------
__global__ __launch_bounds__(256) void k_transpose_s(const float* __restrict__ x,
                                                     short* __restrict__ Xh,
                                                     short* __restrict__ Xl) {
  __shared__ float t[32][33];
  const int l0 = blockIdx.x * 32;
  const int c0 = blockIdx.y * 32;
  const int b  = blockIdx.z;
  const int tx = threadIdx.x;   // 0..31
  const int ty = threadIdx.y;   // 0..7
  const float* xp = x + (size_t)b * C_ * L_;
#pragma unroll
  for (int i = 0; i < 32; i += 8)
    t[ty + i][tx] = xp[(size_t)(c0 + ty + i) * L_ + (l0 + tx)];
  __syncthreads();
#pragma unroll
  for (int i = 0; i < 32; i += 8) {
    float v = t[tx][ty + i];
    short hi = f2bf(v);
    size_t o = ((size_t)b * L_ + l0 + ty + i) * C_ + c0 + tx;
    Xh[o] = hi;
    Xl[o] = f2bf(v - bf2f(hi));
  }
}

// ---------------------------------------------------------------------------
// weight pack: W[256][256] fp32 -> Wt_hi/Wt_lo bf16 [n][k] (transposed+split)
// ---------------------------------------------------------------------------
__global__ __launch_bounds__(256) void k_packw(
    const float* __restrict__ w0, const float* __restrict__ w1,
    const float* __restrict__ w2, const float* __restrict__ w3,
    const float* __restrict__ w4, const float* __restrict__ w5,
    const float* __restrict__ w6,
    short* __restrict__ hi, short* __restrict__ lo) {
  const float* Ws[7] = {w0, w1, w2, w3, w4, w5, w6};
  const int wi = blockIdx.z;
  const float* W = Ws[wi];
  __shared__ float T[32][33];
  const int k0 = blockIdx.x * 32, n0 = blockIdx.y * 32;
  const int tx = threadIdx.x & 31, ty = threadIdx.x >> 5;  // 32 x 8
#pragma unroll
  for (int i = 0; i < 32; i += 8)
    T[ty + i][tx] = W[(size_t)(k0 + ty + i) * 256 + n0 + tx];   // T[k][n]
  __syncthreads();
  short* ho = hi + (size_t)wi * 65536;
  short* lp = lo + (size_t)wi * 65536;
#pragma unroll
  for (int i = 0; i < 32; i += 8) {
    float v = T[tx][ty + i];            // k = k0+tx, n = n0+ty+i
    short h = f2bf(v);
    float r = v - bf2f(h);
    ho[(size_t)(n0 + ty + i) * 256 + k0 + tx] = h;
    lp[(size_t)(n0 + ty + i) * 256 + k0 + tx] = f2bf(r);
  }
}

// ---------------------------------------------------------------------------
// split-bf16 MFMA GEMM with pre-split A planes:
// out = act(A @ W + bias), A = Ah+Al planes [M][256], W = Wh+Wl [n][k].
// C = Ah*Wh + Ah*Wl + Al*Wh (fp32 accum).
// tile 64x64, BK=32, 4 waves (2x2), wave tile 32x32. grid (256,4) = 1024.
// ---------------------------------------------------------------------------
__global__ __launch_bounds__(256, 4) void k_gemm_p(
    const short* __restrict__ Ahp, const short* __restrict__ Alp,
    const short* __restrict__ Whp, const short* __restrict__ Wlp,
    const float* __restrict__ bias,
    short* __restrict__ outH, short* __restrict__ outL,
    float* __restrict__ outF,
    int actGelu, int wantLo, int wantF32) {
  __shared__ __attribute__((aligned(16))) short Ah[2][64 * 32], Al[2][64 * 32];
  __shared__ __attribute__((aligned(16))) short Bh[2][64 * 32], Bl[2][64 * 32];
  const int tid  = threadIdx.x;
  const int lane = tid & 63;
  const int w    = tid >> 6;
  const int wm = w & 1, wn = w >> 1;
  const int m0 = blockIdx.x * 64;
  const int n0 = blockIdx.y * 64;
  const int l15 = lane & 15, lg = lane >> 4;
  const int ar = tid >> 2;       // 0..63 (row within tile, A and B)
  const int ag = tid & 3;        // k-granule

  short8v rah, ral, rbh, rbl;
  auto gload = [&](int ks) {
    const size_t ao = (size_t)(m0 + ar) * 256 + ks * 32 + ag * 8;
    rah = *reinterpret_cast<const short8v*>(&Ahp[ao]);
    ral = *reinterpret_cast<const short8v*>(&Alp[ao]);
    const size_t bo = (size_t)(n0 + ar) * 256 + ks * 32 + ag * 8;
    rbh = *reinterpret_cast<const short8v*>(&Whp[bo]);
    rbl = *reinterpret_cast<const short8v*>(&Wlp[bo]);
  };
  auto lwrite = [&](int buf) {
    const int g = ag ^ (ar & 3);
    *reinterpret_cast<short8v*>(&Ah[buf][ar * 32 + g * 8]) = rah;
    *reinterpret_cast<short8v*>(&Al[buf][ar * 32 + g * 8]) = ral;
    *reinterpret_cast<short8v*>(&Bh[buf][ar * 32 + g * 8]) = rbh;
    *reinterpret_cast<short8v*>(&Bl[buf][ar * 32 + g * 8]) = rbl;
  };

  const f32x4 z4 = {0.f, 0.f, 0.f, 0.f};
  f32x4 acc[2][2];
#pragma unroll
  for (int s = 0; s < 2; ++s)
#pragma unroll
    for (int t = 0; t < 2; ++t) acc[s][t] = z4;

  gload(0);
  lwrite(0);
  __syncthreads();

  for (int ks = 0; ks < 8; ++ks) {
    const int cur = ks & 1;
    if (ks < 7) gload(ks + 1);
    short8v a_h[2], a_l[2], b_h[2], b_l[2];
#pragma unroll
    for (int s = 0; s < 2; ++s) {
      const int m = wm * 32 + s * 16 + l15;
      const int g = lg ^ (m & 3);
      a_h[s] = *reinterpret_cast<const short8v*>(&Ah[cur][m * 32 + g * 8]);
      a_l[s] = *reinterpret_cast<const short8v*>(&Al[cur][m * 32 + g * 8]);
    }
#pragma unroll
    for (int t = 0; t < 2; ++t) {
      const int n = wn * 32 + t * 16 + l15;
      const int g = lg ^ (n & 3);
      b_h[t] = *reinterpret_cast<const short8v*>(&Bh[cur][n * 32 + g * 8]);
      b_l[t] = *reinterpret_cast<const short8v*>(&Bl[cur][n * 32 + g * 8]);
    }
#pragma unroll
    for (int s = 0; s < 2; ++s)
#pragma unroll
      for (int t = 0; t < 2; ++t) {
        acc[s][t] = __builtin_amdgcn_mfma_f32_16x16x32_bf16(a_h[s], b_h[t], acc[s][t], 0, 0, 0);
        acc[s][t] = __builtin_amdgcn_mfma_f32_16x16x32_bf16(a_h[s], b_l[t], acc[s][t], 0, 0, 0);
        acc[s][t] = __builtin_amdgcn_mfma_f32_16x16x32_bf16(a_l[s], b_h[t], acc[s][t], 0, 0, 0);
      }
    if (ks < 7) lwrite(cur ^ 1);
    __syncthreads();
  }

#pragma unroll
  for (int t = 0; t < 2; ++t) {
    const int col = n0 + wn * 32 + t * 16 + l15;
    const float bv = bias[col];
#pragma unroll
    for (int s = 0; s < 2; ++s)
#pragma unroll
      for (int r = 0; r < 4; ++r) {
        const int row = m0 + wm * 32 + s * 16 + lg * 4 + r;
        float v = acc[s][t][r] + bv;
        if (actGelu) v = gelu_exact(v);
        const size_t o = (size_t)row * 256 + col;
        if (wantF32) {
          outF[o] = v;
        } else {
          short hv = f2bf(v);
          outH[o] = hv;
          if (wantLo) outL[o] = f2bf(v - bf2f(hv));
        }
      }
  }
}

// ---------------------------------------------------------------------------
// Gram partials from bf16 K hi-plane: Gp[bh][chunk] = K^T K (64x64), fp32
// ---------------------------------------------------------------------------
__global__ __launch_bounds__(256) void k_gram(const short* __restrict__ Kp,
                                              float* __restrict__ Gp) {
  __shared__ float Ks[64][68];
  const int tid = threadIdx.x;
  const int tm = tid >> 4;
  const int tn = tid & 15;
  const int chunk = blockIdx.x;
  const int h = blockIdx.y;
  const int b = blockIdx.z;
  const size_t base = (size_t)b * L_ * C_ + (size_t)h * HD_ + (size_t)chunk * 256 * C_;
  const int lr = tid >> 2;
  const int lf = tid & 3;
  float acc[4][4] = {};
  for (int st = 0; st < 4; ++st) {
    __syncthreads();
#pragma unroll
    for (int i = 0; i < 4; ++i) {
      int fg = lf * 4 + i;
      short4 s4 = *reinterpret_cast<const short4*>(&Kp[base + (size_t)(st * 64 + lr) * C_ + fg * 4]);
      Ks[lr][fg * 4 + 0] = bf2f(s4.x);
      Ks[lr][fg * 4 + 1] = bf2f(s4.y);
      Ks[lr][fg * 4 + 2] = bf2f(s4.z);
      Ks[lr][fg * 4 + 3] = bf2f(s4.w);
    }
    __syncthreads();
#pragma unroll 16
    for (int r = 0; r < 64; ++r) {
      float4 a  = *reinterpret_cast<const float4*>(&Ks[r][tm << 2]);
      float4 b2 = *reinterpret_cast<const float4*>(&Ks[r][tn << 2]);
      fma16(acc, a, b2);
    }
  }
  const int bh = b * H_ + h;
  float* gp = Gp + ((size_t)bh * 8 + chunk) * 4096;
#pragma unroll
  for (int i = 0; i < 4; ++i)
    *reinterpret_cast<float4*>(&gp[((tm << 2) + i) * 64 + (tn << 2)]) =
        make_float4(acc[i][0], acc[i][1], acc[i][2], acc[i][3]);
}

__global__ __launch_bounds__(256) void k_gram_reduce(const float* __restrict__ Gp,
                                                     float* __restrict__ G) {
  const int bh = blockIdx.x;
  const int tid = threadIdx.x;
  for (int t = tid; t < 4096; t += 256) {
    float s = 0.f;
#pragma unroll
    for (int c = 0; c < 8; ++c) s += Gp[((size_t)bh * 8 + c) * 4096 + t];
    G[(size_t)bh * 4096 + t] = s;
  }
}

// ---------------------------------------------------------------------------
// per-row Lipschitz scale from bf16 Q hi-plane: Scl = 1/(sqrt(q^T G q)+8e-12)
// ---------------------------------------------------------------------------
__global__ __launch_bounds__(256) void k_scale(const short* __restrict__ Qp,
                                               const float* __restrict__ Gm,
                                               float* __restrict__ Scl) {
  __shared__ float QsT[64][68];
  __shared__ float Gs[64][68];
  const int tid = threadIdx.x;
  const int tm = tid >> 4;
  const int tn = tid & 15;
  const int q0 = blockIdx.x * 64;
  const int h  = blockIdx.y;
  const int b  = blockIdx.z;
  const int bh = b * H_ + h;
  const size_t base = (size_t)b * L_ * C_ + (size_t)h * HD_;
  const int lr = tid >> 2;
  const int lf = tid & 3;
#pragma unroll
  for (int i = 0; i < 4; ++i) {
    int fg = lf * 4 + i;
    short4 s4 = *reinterpret_cast<const short4*>(&Qp[base + (size_t)(q0 + lr) * C_ + fg * 4]);
    QsT[fg * 4 + 0][lr] = bf2f(s4.x);
    QsT[fg * 4 + 1][lr] = bf2f(s4.y);
    QsT[fg * 4 + 2][lr] = bf2f(s4.z);
    QsT[fg * 4 + 3][lr] = bf2f(s4.w);
    float4 g = *reinterpret_cast<const float4*>(&Gm[(size_t)bh * 4096 + lr * 64 + fg * 4]);
    *reinterpret_cast<float4*>(&Gs[lr][fg * 4]) = g;
  }
  __syncthreads();
  float t4[4][4] = {};
#pragma unroll 16
  for (int e = 0; e < 64; ++e) {
    float4 a  = *reinterpret_cast<const float4*>(&QsT[e][tm << 2]);
    float4 b2 = *reinterpret_cast<const float4*>(&Gs[e][tn << 2]);
    fma16(t4, a, b2);
  }
  float r2[4];
#pragma unroll
  for (int i = 0; i < 4; ++i) {
    r2[i] = t4[i][0] * QsT[(tn << 2) + 0][(tm << 2) + i]
          + t4[i][1] * QsT[(tn << 2) + 1][(tm << 2) + i]
          + t4[i][2] * QsT[(tn << 2) + 2][(tm << 2) + i]
          + t4[i][3] * QsT[(tn << 2) + 3][(tm << 2) + i];
#pragma unroll
    for (int o = 8; o; o >>= 1) r2[i] += __shfl_xor(r2[i], o);
  }
  if (tn == 0) {
#pragma unroll
    for (int i = 0; i < 4; ++i) {
      float rr = fmaxf(r2[i], 0.f);
      Scl[(size_t)bh * L_ + q0 + (tm << 2) + i] = 1.0f / (sqrtf(rr) + 8e-12f);
    }
  }
}

// ---------------------------------------------------------------------------
// transpose V hi-plane [B*L][C] -> Vt[bh][64 d][L] (bf16)
// ---------------------------------------------------------------------------
__global__ __launch_bounds__(256) void k_packt_v(const short* __restrict__ Vp,
                                                 short* __restrict__ Vt) {
  __shared__ __attribute__((aligned(16))) short T[64][68];
  const int lt = blockIdx.x;
  const int h = blockIdx.y, b = blockIdx.z;
  const int bh = b * H_ + h;
  const int tid = threadIdx.x;
#pragma unroll
  for (int i = 0; i < 4; ++i) {
    int idx = tid + 256 * i;     // 64 l x 16 short4
    int l = idx >> 4;
    int c4 = idx & 15;
    short4 v = *reinterpret_cast<const short4*>(
        &Vp[(size_t)(b * L_ + lt * 64 + l) * C_ + h * HD_ + c4 * 4]);
    *reinterpret_cast<short4*>(&T[l][c4 * 4]) = v;
  }
  __syncthreads();
  const int d = tid >> 2;        // 0..63
  const int j = tid & 3;
#pragma unroll
  for (int i = 0; i < 4; ++i) {
    int l = j * 4 + i * 16;
    short4 s;
    s.x = T[l + 0][d];
    s.y = T[l + 1][d];
    s.z = T[l + 2][d];
    s.w = T[l + 3][d];
    *reinterpret_cast<short4*>(&Vt[((size_t)bh * HD_ + d) * L_ + lt * 64 + l]) = s;
  }
}

// ---------------------------------------------------------------------------
// MFMA attention, swapped QK^T (S^T = mfma(K,Q)): 4x fewer P LDS ops.
// block = 128 q rows, 4 waves x 32 q. XCD-aware 1D grid decode.
// Fragment maps: A row=l&15,k=(l>>4)*8+j; B col=l&15; C row=(l>>4)*4+r, col=l&15.
// ---------------------------------------------------------------------------
__device__ __forceinline__ int swz(int r, int c) {
  return (r * 64 + c) ^ ((r & 7) << 3);
}

__global__ __launch_bounds__(256) void k_attn_mfma(
    const short* __restrict__ Qp, const short* __restrict__ Kp,
    const short* __restrict__ Vt, const float* __restrict__ Scl,
    short* __restrict__ AOh, short* __restrict__ AOl) {
  __shared__ __attribute__((aligned(16))) short Ks[2][64 * 64];   // K[key][d] swz
  __shared__ __attribute__((aligned(16))) short Vs[2][64 * 64];   // V^T[d][key] swz
  __shared__ __attribute__((aligned(16))) short Ps[4][32 * 64];   // P[q][k] swz
  const int tid  = threadIdx.x;
  const int lane = tid & 63;
  const int w    = tid >> 6;
  // XCD-aware decode: u = xcd + 8*(qi + 16*g); bh = g*8+xcd
  const int u   = blockIdx.x;
  const int xcd = u & 7;
  const int qi  = (u >> 3) & 15;
  const int g   = u >> 7;
  const int bh  = g * 8 + xcd;
  const int b = bh >> 2, h = bh & 3;
  const size_t rowbase = (size_t)b * L_ * C_ + (size_t)h * HD_;   // plane base
  const size_t vtb = (size_t)bh * HD_ * L_;
  const int q0 = qi * 128 + w * 32;
  const int l15 = lane & 15;
  const int lg  = lane >> 4;
  const int srow = tid >> 3;     // 0..31
  const int sseg = tid & 7;      // 0..7

  // Q fragments (B-operand): aq[sub][ch] = Q[q0+sub*16+l15][ch*32+lg*8 ..]
  short8v aq[2][2];
#pragma unroll
  for (int sub = 0; sub < 2; ++sub)
#pragma unroll
    for (int ch = 0; ch < 2; ++ch)
      aq[sub][ch] = *reinterpret_cast<const short8v*>(
          &Qp[rowbase + (size_t)(q0 + sub * 16 + l15) * C_ + ch * 32 + lg * 8]);

  float sr[2];   // scale for q = q0 + sub*16 + l15
#pragma unroll
  for (int sub = 0; sub < 2; ++sub)
    sr[sub] = Scl[(size_t)bh * L_ + q0 + sub * 16 + l15];

  short8v stK0, stK1, stV0, stV1;
  auto stage_load = [&](int kt) {
    stK0 = *reinterpret_cast<const short8v*>(&Kp[rowbase + (size_t)(kt * 64 + srow) * C_ + sseg * 8]);
    stK1 = *reinterpret_cast<const short8v*>(&Kp[rowbase + (size_t)(kt * 64 + 32 + srow) * C_ + sseg * 8]);
    stV0 = *reinterpret_cast<const short8v*>(&Vt[vtb + (size_t)srow * L_ + kt * 64 + sseg * 8]);
    stV1 = *reinterpret_cast<const short8v*>(&Vt[vtb + (size_t)(32 + srow) * L_ + kt * 64 + sseg * 8]);
  };
  auto stage_write = [&](int buf) {
    *reinterpret_cast<short8v*>(&Ks[buf][swz(srow, sseg * 8)]) = stK0;
    *reinterpret_cast<short8v*>(&Ks[buf][swz(32 + srow, sseg * 8)]) = stK1;
    *reinterpret_cast<short8v*>(&Vs[buf][swz(srow, sseg * 8)]) = stV0;
    *reinterpret_cast<short8v*>(&Vs[buf][swz(32 + srow, sseg * 8)]) = stV1;
  };

  const f32x4 z4 = {0.f, 0.f, 0.f, 0.f};
  float lsum[2] = {0.f, 0.f};
  f32x4 oacc[2][4];
#pragma unroll
  for (int s = 0; s < 2; ++s)
#pragma unroll
    for (int d = 0; d < 4; ++d) oacc[s][d] = z4;

  stage_load(0);
  stage_write(0);
  __syncthreads();

  for (int kt = 0; kt < 32; ++kt) {
    const int cur = kt & 1;
    if (kt < 31) stage_load(kt + 1);

    // ---- S^T = mfma(K, Q): lane holds S^T[key=nt*16+lg*4+r][q=sub*16+l15]
    f32x4 sacc[2][4];
#pragma unroll
    for (int s = 0; s < 2; ++s)
#pragma unroll
      for (int nt = 0; nt < 4; ++nt) sacc[s][nt] = z4;
#pragma unroll
    for (int nt = 0; nt < 4; ++nt) {
      short8v kb0 = *reinterpret_cast<const short8v*>(&Ks[cur][swz(nt * 16 + l15, lg * 8)]);
      short8v kb1 = *reinterpret_cast<const short8v*>(&Ks[cur][swz(nt * 16 + l15, 32 + lg * 8)]);
#pragma unroll
      for (int sub = 0; sub < 2; ++sub) {
        sacc[sub][nt] = __builtin_amdgcn_mfma_f32_16x16x32_bf16(kb0, aq[sub][0], sacc[sub][nt], 0, 0, 0);
        sacc[sub][nt] = __builtin_amdgcn_mfma_f32_16x16x32_bf16(kb1, aq[sub][1], sacc[sub][nt], 0, 0, 0);
      }
    }

    // ---- exp + packed P store: lane writes 4 consecutive k per (sub,nt)
#pragma unroll
    for (int sub = 0; sub < 2; ++sub)
#pragma unroll
      for (int nt = 0; nt < 4; ++nt) {
        float p0 = __expf(sacc[sub][nt][0] * sr[sub]);
        float p1 = __expf(sacc[sub][nt][1] * sr[sub]);
        float p2 = __expf(sacc[sub][nt][2] * sr[sub]);
        float p3 = __expf(sacc[sub][nt][3] * sr[sub]);
        lsum[sub] += (p0 + p1) + (p2 + p3);
        unsigned int w0 = (unsigned short)f2bf(p0) | ((unsigned int)(unsigned short)f2bf(p1) << 16);
        unsigned int w1 = (unsigned short)f2bf(p2) | ((unsigned int)(unsigned short)f2bf(p3) << 16);
        uint2 pk; pk.x = w0; pk.y = w1;
        *reinterpret_cast<uint2*>(&Ps[w][swz(sub * 16 + l15, nt * 16 + lg * 4)]) = pk;
      }
    asm volatile("s_waitcnt lgkmcnt(0)");
    __builtin_amdgcn_sched_barrier(0);

    // ---- PV: out[q][d] = P[q][k] V[k][d]
    short8v pa[2][2];
#pragma unroll
    for (int sub = 0; sub < 2; ++sub) {
      pa[sub][0] = *reinterpret_cast<const short8v*>(&Ps[w][swz(sub * 16 + l15, lg * 8)]);
      pa[sub][1] = *reinterpret_cast<const short8v*>(&Ps[w][swz(sub * 16 + l15, 32 + lg * 8)]);
    }
#pragma unroll
    for (int dt = 0; dt < 4; ++dt) {
      short8v vb0 = *reinterpret_cast<const short8v*>(&Vs[cur][swz(dt * 16 + l15, lg * 8)]);
      short8v vb1 = *reinterpret_cast<const short8v*>(&Vs[cur][swz(dt * 16 + l15, 32 + lg * 8)]);
#pragma unroll
      for (int sub = 0; sub < 2; ++sub) {
        oacc[sub][dt] = __builtin_amdgcn_mfma_f32_16x16x32_bf16(pa[sub][0], vb0, oacc[sub][dt], 0, 0, 0);
        oacc[sub][dt] = __builtin_amdgcn_mfma_f32_16x16x32_bf16(pa[sub][1], vb1, oacc[sub][dt], 0, 0, 0);
      }
    }
    __syncthreads();
    if (kt < 31) {
      stage_write(cur ^ 1);
      __syncthreads();
    }
  }

  // lsum: sum partial (per-lg) contributions across lanes sharing l15
#pragma unroll
  for (int sub = 0; sub < 2; ++sub) {
    lsum[sub] += __shfl_xor(lsum[sub], 16);
    lsum[sub] += __shfl_xor(lsum[sub], 32);
  }

  // epilogue: out row q = q0+sub*16+lg*4+r (C-layout), col d = dt*16+l15
#pragma unroll
  for (int sub = 0; sub < 2; ++sub)
#pragma unroll
    for (int r = 0; r < 4; ++r) {
      const float inv = 1.0f / __shfl(lsum[sub], lg * 4 + r);
      const int q = q0 + sub * 16 + lg * 4 + r;
#pragma unroll
      for (int dt = 0; dt < 4; ++dt) {
        float v = oacc[sub][dt][r] * inv;
        short hv = f2bf(v);
        const size_t o = rowbase + (size_t)q * C_ + dt * 16 + l15;
        AOh[o] = hv;
        AOl[o] = f2bf(v - bf2f(hv));
      }
    }
}

// ---------------------------------------------------------------------------
// LayerNorm(C) + ELU + residual + transpose back to [B][C][L]
// ---------------------------------------------------------------------------
__global__ __launch_bounds__(256) void k_ln(const float* __restrict__ PO,
                                            const float* __restrict__ x,
                                            const float* __restrict__ g,
                                            const float* __restrict__ bta,
                                            float* __restrict__ out) {
  __shared__ float buf[32][257];
  __shared__ float mu_s[32], rs_s[32];
  __shared__ float gs[256], bs[256];
  const int b  = blockIdx.y;
  const int l0 = blockIdx.x * 32;
  const int tid = threadIdx.x;
  gs[tid] = g[tid];
  bs[tid] = bta[tid];
#pragma unroll 8
  for (int r = 0; r < 32; ++r)
    buf[r][tid] = PO[((size_t)b * L_ + l0 + r) * C_ + tid];
  __syncthreads();
  {
    const int r  = tid >> 3;
    const int c0 = tid & 7;
    float s1 = 0.f;
#pragma unroll
    for (int i = 0; i < 32; ++i) s1 += buf[r][c0 + (i << 3)];
#pragma unroll
    for (int o = 4; o; o >>= 1) s1 += __shfl_xor(s1, o);
    float mu = s1 * (1.0f / 256.0f);
    float s2 = 0.f;
#pragma unroll
    for (int i = 0; i < 32; ++i) {
      float dv = buf[r][c0 + (i << 3)] - mu;
      s2 += dv * dv;
    }
#pragma unroll
    for (int o = 4; o; o >>= 1) s2 += __shfl_xor(s2, o);
    if (c0 == 0) {
      mu_s[r] = mu;
      rs_s[r] = rsqrtf(s2 * (1.0f / 256.0f) + 1e-5f);
    }
  }
  __syncthreads();
  const int tl = tid & 31;
  const int tc = tid >> 5;
  const float mu = mu_s[tl];
  const float rs = rs_s[tl];
#pragma unroll 8
  for (int c = tc; c < 256; c += 8) {
    float y = (buf[tl][c] - mu) * rs * gs[c] + bs[c];
    float e = (y > 0.f) ? y : (__expf(y) - 1.0f);
    size_t idx = ((size_t)b * C_ + c) * L_ + l0 + tl;
    out[idx] = e + x[idx];
  }
}

// ---------------------------------------------------------------------------
extern "C" void kernel_launch(void* const* d_in, const int* in_sizes, int n_in,
                              void* d_out, int out_size, void* d_ws, size_t ws_size,
                              hipStream_t stream) {
  const float* x_in = (const float*)d_in[0];
  const float* q_w1 = (const float*)d_in[1];
  const float* q_b1 = (const float*)d_in[2];
  const float* q_w2 = (const float*)d_in[3];
  const float* q_b2 = (const float*)d_in[4];
  const float* k_w1 = (const float*)d_in[5];
  const float* k_b1 = (const float*)d_in[6];
  const float* k_w2 = (const float*)d_in[7];
  const float* k_b2 = (const float*)d_in[8];
  const float* v_w1 = (const float*)d_in[9];
  const float* v_b1 = (const float*)d_in[10];
  const float* v_w2 = (const float*)d_in[11];
  const float* v_b2 = (const float*)d_in[12];
  const float* o_w  = (const float*)d_in[13];
  const float* o_b  = (const float*)d_in[14];
  const float* ln_g = (const float*)d_in[15];
  const float* ln_b = (const float*)d_in[16];
  float* out = (float*)d_out;

  const size_t NB = (size_t)B_ * L_ * C_;          // 4,194,304 elements
  short* Xh = (short*)d_ws;                        // 8MB each plane
  short* Xl = Xh + NB;
  short* Hh = Xl + NB;
  short* Hl = Hh + NB;
  short* Qp = Hl + NB;
  short* Kp = Qp + NB;
  short* Vp = Kp + NB;
  float* Gp = (float*)(Vp + NB);                   // 4MB
  float* G  = Gp + (size_t)32 * 8 * 4096;          // 512KB
  float* Scl = G + (size_t)32 * 4096;              // 256KB
  short* Whi = (short*)(Scl + (size_t)32 * 2048);  // 7*128KB
  short* Wlo = Whi + (size_t)7 * 65536;
  // aliases (lifetimes verified):
  float* PO  = (float*)Xh;   // o-proj out (fp32), Xh/Xl free after mlp1-v
  short* AOh = Hh;           // attn out hi, Hh free after mlp2-v
  short* Vt  = Hl;           // V^T bf16, Hl free after mlp2-v
  short* AOl = Vp;           // attn out lo, Vp free after k_packt_v

  const size_t WN = 65536;
  dim3 gg(256, 4);           // 1024 blocks, 64x64 tiles

  k_packw<<<dim3(8, 8, 7), 256, 0, stream>>>(q_w1, q_w2, k_w1, k_w2, v_w1, v_w2, o_w, Whi, Wlo);
  k_transpose_s<<<dim3(L_ / 32, C_ / 32, B_), dim3(32, 8), 0, stream>>>(x_in, Xh, Xl);

  k_gemm_p<<<gg, 256, 0, stream>>>(Xh, Xl, Whi + 0 * WN, Wlo + 0 * WN, q_b1, Hh, Hl, nullptr, 1, 1, 0);
  k_gemm_p<<<gg, 256, 0, stream>>>(Hh, Hl, Whi + 1 * WN, Wlo + 1 * WN, q_b2, Qp, nullptr, nullptr, 0, 0, 0);
  k_gemm_p<<<gg, 256, 0, stream>>>(Xh, Xl, Whi + 2 * WN, Wlo + 2 * WN, k_b1, Hh, Hl, nullptr, 1, 1, 0);
  k_gemm_p<<<gg, 256, 0, stream>>>(Hh, Hl, Whi + 3 * WN, Wlo + 3 * WN, k_b2, Kp, nullptr, nullptr, 0, 0, 0);
  k_gemm_p<<<gg, 256, 0, stream>>>(Xh, Xl, Whi + 4 * WN, Wlo + 4 * WN, v_b1, Hh, Hl, nullptr, 1, 1, 0);
  k_gemm_p<<<gg, 256, 0, stream>>>(Hh, Hl, Whi + 5 * WN, Wlo + 5 * WN, v_b2, Vp, nullptr, nullptr, 0, 0, 0);

  k_gram<<<dim3(8, H_, B_), 256, 0, stream>>>(Kp, Gp);
  k_gram_reduce<<<dim3(32), 256, 0, stream>>>(Gp, G);
  k_scale<<<dim3(L_ / 64, H_, B_), 256, 0, stream>>>(Qp, G, Scl);
  k_packt_v<<<dim3(L_ / 64, H_, B_), 256, 0, stream>>>(Vp, Vt);

  k_attn_mfma<<<dim3(512), 256, 0, stream>>>(Qp, Kp, Vt, Scl, AOh, AOl);

  k_gemm_p<<<gg, 256, 0, stream>>>(AOh, AOl, Whi + 6 * WN, Wlo + 6 * WN, o_b, nullptr, nullptr, PO, 0, 0, 1);

  k_ln<<<dim3(L_ / 32, B_), 256, 0, stream>>>(PO, x_in, ln_g, ln_b, out);
}